// Round 8
// baseline (478.473 us; speedup 1.0000x reference)
//
#include <hip/hip_runtime.h>

#define NN 20000      // nodes
#define NNP 20032     // padded rows (64-row GEMM tiles read past NN)
#define NH 128        // hidden
#define NG 64         // graphs
#define NLAY 3
#define NCH 5         // 4 splits + main
#define GEPS 1e-5f
#define GSLOPE 0.01f

typedef unsigned short u16;
typedef unsigned int u32;
typedef __attribute__((ext_vector_type(8))) short short8;
typedef __attribute__((ext_vector_type(4))) float float4v;
typedef __attribute__((ext_vector_type(2))) float f32x2;

__device__ __forceinline__ u16 f2bf(float f) {
  union { float f; u32 u; } v; v.f = f;
  u32 r = (v.u + 0x7fffu + ((v.u >> 16) & 1u)) >> 16;
  return (u16)r;
}

struct ZP {
  const u16* A[NCH];     // GEMM input = Xo of previous layer (bf16, NN rows)
  const u16* W[NCH];     // GEMM weight, bf16 transposed [N][K]
  u16* Y[NCH];           // GEMM output / gather source (bf16)
  int ystride[NCH];      // row stride of Y in elements (256 for ydual, 128 else)
  u16* Xo[NCH];          // post-agg pre-norm (bf16, stride NH)
  const float* bias[NCH];
  const float* gw[NCH];  // this layer's norm weight (for k_norm2)
  const float* gb[NCH];
  const float* gms[NCH];
  const float* pgw[NCH]; // PREVIOUS layer's norm weight (for fused gemm staging)
  const float* pgb[NCH];
  int colbase[NCH];
};

struct ES4 {
  const int* e[4];
  int cnt[4];
  int off[4];
};

// ---------------- setup kernels ----------------

// r20: parallel two-phase scan (replaced 5-CU serial scan: −10.6 µs).
// r21: counting-sort degree permutation folded in — dual-agg blocks process
// nodes degree-DESCENDING (LPT schedule) so the dispatch tail is the lightest
// work. Per-node accumulation order unchanged -> bit-identical output.
__global__ __launch_bounds__(1024) void k_scanA(const int* __restrict__ deg,
                                                int* __restrict__ indptr,
                                                float* __restrict__ dinv,
                                                int* __restrict__ tsum,
                                                int* __restrict__ bins) {
  int s = blockIdx.y, tile = blockIdx.x;
  int t = threadIdx.x;
  int idx = tile * 1024 + t;
  int v = 0;
  if (idx < NN) {
    v = deg[s * NN + idx];
    dinv[s * NN + idx] = rsqrtf((float)v + 1.0f);
    if (s == 0) atomicAdd(&bins[v < 255 ? v : 255], 1);  // degree histogram
  }
  int lane = t & 63, wv = t >> 6;  // 16 waves
  __shared__ int wsum[16];
  int x = v;
#pragma unroll
  for (int o = 1; o < 64; o <<= 1) {
    int y = __shfl_up(x, o);
    if (lane >= o) x += y;
  }
  if (lane == 63) wsum[wv] = x;
  __syncthreads();
  if (wv == 0) {
    int y = (lane < 16) ? wsum[lane] : 0;
#pragma unroll
    for (int o = 1; o < 16; o <<= 1) {
      int z = __shfl_up(y, o);
      if (lane >= o) y += z;
    }
    if (lane < 16) wsum[lane] = y;
  }
  __syncthreads();
  int waveoff = (wv == 0) ? 0 : wsum[wv - 1];
  int excl = waveoff + x - v;  // exclusive within tile
  if (idx < NN) indptr[s * (NN + 1) + idx] = excl;
  if (t == 1023) tsum[s * 20 + tile] = waveoff + x;  // tile total
}

__global__ __launch_bounds__(128) void k_scanB(const int* __restrict__ tsum,
                                               int* __restrict__ toff,
                                               int* __restrict__ indptr,
                                               int* __restrict__ cursor,
                                               const int* __restrict__ batch,
                                               int* __restrict__ counts,
                                               int* __restrict__ gstart,
                                               const int* __restrict__ bins,
                                               int* __restrict__ binoff) {
  int t = threadIdx.x;
  if (t < 4) {
    int run = 0;
    for (int i = 0; i < 20; i++) {
      toff[t * 20 + i] = run;
      run += tsum[t * 20 + i];
    }
    indptr[t * (NN + 1) + NN] = run;
    cursor[t * (NN + 1) + NN] = run;
  }
  if (t == 4) {  // descending-degree bin offsets (LPT order)
    int off = 0;
    for (int b = 255; b >= 0; b--) {
      binoff[b] = off;
      off += bins[b];
    }
  }
  if (t >= 64) {
    int g = t - 64;  // per-graph start/count via binary search (batch sorted)
    auto lb = [&](int key) {
      int lo = 0, hi = NN;
      while (lo < hi) {
        int mid = (lo + hi) >> 1;
        if (batch[mid] < key) lo = mid + 1; else hi = mid;
      }
      return lo;
    };
    int a = lb(g), b = lb(g + 1);
    gstart[g] = a;
    counts[g] = b - a;
  }
}

__global__ __launch_bounds__(1024) void k_scanC(int* __restrict__ indptr,
                                                int* __restrict__ cursor,
                                                const int* __restrict__ toff,
                                                const int* __restrict__ deg,
                                                int* __restrict__ binoff,
                                                int* __restrict__ perm) {
  int s = blockIdx.y, tile = blockIdx.x;
  int idx = tile * 1024 + threadIdx.x;
  if (idx < NN) {
    int v = indptr[s * (NN + 1) + idx] + toff[s * 20 + tile];
    indptr[s * (NN + 1) + idx] = v;
    cursor[s * (NN + 1) + idx] = v;
    if (s == 0) {  // scatter node into degree-descending slot
      int d = deg[idx];
      int pos = atomicAdd(&binoff[d < 255 ? d : 255], 1);
      perm[pos] = idx;
    }
  }
}

// packed entry: low 16 = src (NN < 2^16), high 16 = coef as bf16.
__global__ void k_fill(ES4 es, const float* __restrict__ dinv, int* __restrict__ cursor,
                       u32* __restrict__ ent) {
  int s = blockIdx.y;
  int i = blockIdx.x * 256 + threadIdx.x;
  int E = es.cnt[s];
  if (i >= E) return;
  int src = es.e[s][i];
  int dst = es.e[s][E + i];
  int pos = atomicAdd(&cursor[s * (NN + 1) + dst], 1);
  float c = dinv[s * NN + src] * dinv[s * NN + dst];
  ent[es.off[s] + pos] = (u32)src | ((u32)f2bf(c) << 16);
}

// fused setup: y<4 -> deg histogram for edge set y; y in 4..10 -> weight transpose
// fp32[K][N]->bf16[N][K] for mat y-4 (x<16).
__global__ __launch_bounds__(256) void k_setup(ES4 es, int* __restrict__ deg,
                                               const float* __restrict__ embW,
                                               const float* __restrict__ locW,
                                               const float* __restrict__ mainW,
                                               u16* __restrict__ wt) {
  int ybk = blockIdx.y;
  if (ybk < 4) {
    int s = ybk;
    int i = blockIdx.x * 256 + threadIdx.x;
    int E = es.cnt[s];
    if (i < E) atomicAdd(&deg[s * NN + es.e[s][E + i]], 1);
    return;
  }
  if (blockIdx.x >= 16) return;
  int mat = ybk - 4;
  const float* W = (mat == 0) ? embW : ((mat <= 3) ? locW + (mat - 1) * NH * NH
                                                   : mainW + (mat - 4) * NH * NH);
  int tile = blockIdx.x;
  int tk = (tile >> 2) * 32;
  int tn = (tile & 3) * 32;
  __shared__ float tl[32][33];
  int c = threadIdx.x & 31, r = threadIdx.x >> 5;
#pragma unroll
  for (int rr = 0; rr < 32; rr += 8)
    tl[r + rr][c] = W[(size_t)(tk + r + rr) * NH + tn + c];
  __syncthreads();
#pragma unroll
  for (int rr = 0; rr < 32; rr += 8)
    wt[(size_t)mat * NH * NH + (size_t)(tn + r + rr) * NH + tk + c] = f2bf(tl[c][r + rr]);
}

// ---------------- compute kernels ----------------

// Fused embedding + layer-0 GEMMs: per 64-row tile,
//   h = bf16(x) @ embW + embb       (h lives only in LDS, bf16)
//   ydual[:,0:128]   = h @ locW0    (shared by split chains 0..3)
//   ydual[:,128:256] = h @ mainW0
__global__ __launch_bounds__(256) void k_gemm0(const float* __restrict__ x,
                                               const u16* __restrict__ wt,
                                               const float* __restrict__ embb,
                                               u16* __restrict__ ydual) {
  __shared__ u16 As[64][136];
  __shared__ u16 Bs[128][136];
  int t = threadIdx.x;
  int row0 = blockIdx.x * 64;
  int c = t & 15, rs = t >> 4;
#pragma unroll
  for (int pass = 0; pass < 4; pass++) {
    int r = pass * 16 + rs;
    int gr = row0 + r;
    uint4 o = make_uint4(0, 0, 0, 0);
    if (gr < NN) {
      float4 a = *(const float4*)(x + (size_t)gr * NH + c * 8);
      float4 b = *(const float4*)(x + (size_t)gr * NH + c * 8 + 4);
      o.x = f2bf(a.x) | ((u32)f2bf(a.y) << 16);
      o.y = f2bf(a.z) | ((u32)f2bf(a.w) << 16);
      o.z = f2bf(b.x) | ((u32)f2bf(b.y) << 16);
      o.w = f2bf(b.z) | ((u32)f2bf(b.w) << 16);
    }
    *(uint4*)(&As[r][c * 8]) = o;
  }
#pragma unroll
  for (int pass = 0; pass < 8; pass++) {
    int n = pass * 16 + rs;
    *(uint4*)(&Bs[n][c * 8]) = *(const uint4*)(wt + (size_t)n * NH + c * 8);  // embW
  }
  __syncthreads();
  int lane = t & 63, w = t >> 6;
  int m16 = lane & 15, quad = lane >> 4;
  float4v acc[8];
#pragma unroll
  for (int i = 0; i < 8; i++) acc[i] = (float4v)(0.f);
#pragma unroll
  for (int kk = 0; kk < 4; kk++) {
    short8 av = *(const short8*)(&As[w * 16 + m16][kk * 32 + quad * 8]);
#pragma unroll
    for (int ct = 0; ct < 8; ct++) {
      short8 bv = *(const short8*)(&Bs[ct * 16 + m16][kk * 32 + quad * 8]);
      acc[ct] = __builtin_amdgcn_mfma_f32_16x16x32_bf16(av, bv, acc[ct], 0, 0, 0);
    }
  }
  __syncthreads();  // stage-1 LDS reads complete
#pragma unroll
  for (int ct = 0; ct < 8; ct++) {
    float bv = embb[ct * 16 + m16];
#pragma unroll
    for (int r = 0; r < 4; r++)
      As[w * 16 + quad * 4 + r][ct * 16 + m16] = f2bf(acc[ct][r] + bv);
  }
  {
    const u16* wl = wt + (size_t)1 * NH * NH;  // locW0
#pragma unroll
    for (int pass = 0; pass < 8; pass++) {
      int n = pass * 16 + rs;
      *(uint4*)(&Bs[n][c * 8]) = *(const uint4*)(wl + (size_t)n * NH + c * 8);
    }
  }
  __syncthreads();
  float4v acc0[8];
#pragma unroll
  for (int i = 0; i < 8; i++) acc0[i] = (float4v)(0.f);
#pragma unroll
  for (int kk = 0; kk < 4; kk++) {
    short8 av = *(const short8*)(&As[w * 16 + m16][kk * 32 + quad * 8]);
#pragma unroll
    for (int ct = 0; ct < 8; ct++) {
      short8 bv = *(const short8*)(&Bs[ct * 16 + m16][kk * 32 + quad * 8]);
      acc0[ct] = __builtin_amdgcn_mfma_f32_16x16x32_bf16(av, bv, acc0[ct], 0, 0, 0);
    }
  }
  __syncthreads();  // stage-2 Bs reads complete
  {
    const u16* wm = wt + (size_t)4 * NH * NH;  // mainW0
#pragma unroll
    for (int pass = 0; pass < 8; pass++) {
      int n = pass * 16 + rs;
      *(uint4*)(&Bs[n][c * 8]) = *(const uint4*)(wm + (size_t)n * NH + c * 8);
    }
  }
  __syncthreads();
  float4v acc4[8];
#pragma unroll
  for (int i = 0; i < 8; i++) acc4[i] = (float4v)(0.f);
#pragma unroll
  for (int kk = 0; kk < 4; kk++) {
    short8 av = *(const short8*)(&As[w * 16 + m16][kk * 32 + quad * 8]);
#pragma unroll
    for (int ct = 0; ct < 8; ct++) {
      short8 bv = *(const short8*)(&Bs[ct * 16 + m16][kk * 32 + quad * 8]);
      acc4[ct] = __builtin_amdgcn_mfma_f32_16x16x32_bf16(av, bv, acc4[ct], 0, 0, 0);
    }
  }
  __syncthreads();  // stage-3 LDS reads complete; As/Bs free for bounce
#pragma unroll
  for (int ct = 0; ct < 8; ct++) {
#pragma unroll
    for (int r = 0; r < 4; r++) {
      As[w * 16 + quad * 4 + r][ct * 16 + m16] = f2bf(acc0[ct][r]);
      Bs[w * 16 + quad * 4 + r][ct * 16 + m16] = f2bf(acc4[ct][r]);
    }
  }
  __syncthreads();
#pragma unroll
  for (int pass = 0; pass < 4; pass++) {
    int r = pass * 16 + rs;
    int gr = row0 + r;
    if (gr < NN) {
      *(uint4*)(ydual + (size_t)gr * 256 + c * 8) = *(const uint4*)(&As[r][c * 8]);
      *(uint4*)(ydual + (size_t)gr * 256 + 128 + c * 8) = *(const uint4*)(&Bs[r][c * 8]);
    }
  }
}

// Y[z] = norm_affine(Xo_prev[z]) @ Wt[z]^T. The previous layer's graph-norm +
// leaky is applied during A-staging from per-(chain,graph) {mm=ms*mean, inv}
// (aff buffer) + layer params (pgw/pgb). Expression shape matches k_norm2's old
// Xn path exactly -> bf16-rounded A operand is bit-identical (r15 fusion:
// removes the 102 MB Xn write+read round trip).
__global__ __launch_bounds__(256) void k_gemm_bf(ZP p, const int* __restrict__ batch,
                                                 const float* __restrict__ aff) {
  int zi = blockIdx.y;
  const u16* __restrict__ X = p.A[zi];
  const u16* __restrict__ Wt = p.W[zi];
  u16* __restrict__ Y = p.Y[zi];
  const float* __restrict__ gw = p.pgw[zi];
  const float* __restrict__ gb = p.pgb[zi];
  int yst = p.ystride[zi];
  __shared__ u16 As[64][136];   // +8 pad: 2-way bank aliasing only
  __shared__ u16 Bs[128][136];
  int t = threadIdx.x;
  int row0 = blockIdx.x * 64;
  int c = t & 15, rs = t >> 4;
  float4 wA = *(const float4*)(gw + c * 8);
  float4 wB = *(const float4*)(gw + c * 8 + 4);
  float4 bA = *(const float4*)(gb + c * 8);
  float4 bB = *(const float4*)(gb + c * 8 + 4);
  float wv8[8] = {wA.x, wA.y, wA.z, wA.w, wB.x, wB.y, wB.z, wB.w};
  float bv8[8] = {bA.x, bA.y, bA.z, bA.w, bB.x, bB.y, bB.z, bB.w};
#pragma unroll
  for (int pass = 0; pass < 4; pass++) {
    int r = pass * 16 + rs;
    int gr = row0 + r;
    int grc = (gr < NN) ? gr : (NN - 1);  // clamp: stores are guarded anyway
    int gg = batch[grc];
    const float* ab = aff + ((size_t)zi * NG + gg) * 2 * NH;
    uint4 xv = *(const uint4*)(X + (size_t)grc * NH + c * 8);
    float4 mA = *(const float4*)(ab + c * 8);
    float4 mB = *(const float4*)(ab + c * 8 + 4);
    float4 iA = *(const float4*)(ab + NH + c * 8);
    float4 iB = *(const float4*)(ab + NH + c * 8 + 4);
    float mm[8] = {mA.x, mA.y, mA.z, mA.w, mB.x, mB.y, mB.z, mB.w};
    float iv[8] = {iA.x, iA.y, iA.z, iA.w, iB.x, iB.y, iB.z, iB.w};
    u32 xw[4] = {xv.x, xv.y, xv.z, xv.w};
    uint4 ou;
    u32* op = (u32*)&ou;
#pragma unroll
    for (int j = 0; j < 4; j++) {
      float v0 = __uint_as_float(xw[j] << 16);
      float v1 = __uint_as_float(xw[j] & 0xffff0000u);
      float o0 = wv8[2 * j] * (v0 - mm[2 * j]) * iv[2 * j] + bv8[2 * j];
      float o1 = wv8[2 * j + 1] * (v1 - mm[2 * j + 1]) * iv[2 * j + 1] + bv8[2 * j + 1];
      o0 = (o0 >= 0.f) ? o0 : GSLOPE * o0;
      o1 = (o1 >= 0.f) ? o1 : GSLOPE * o1;
      op[j] = (u32)f2bf(o0) | ((u32)f2bf(o1) << 16);
    }
    *(uint4*)(&As[r][c * 8]) = ou;
  }
#pragma unroll
  for (int pass = 0; pass < 8; pass++) {
    int n = pass * 16 + rs;
    *(uint4*)(&Bs[n][c * 8]) = *(const uint4*)(Wt + (size_t)n * NH + c * 8);
  }
  __syncthreads();
  int lane = t & 63, w = t >> 6;
  int m16 = lane & 15, quad = lane >> 4;
  float4v acc[8];
#pragma unroll
  for (int i = 0; i < 8; i++) acc[i] = (float4v)(0.f);
#pragma unroll
  for (int kk = 0; kk < 4; kk++) {
    short8 av = *(const short8*)(&As[w * 16 + m16][kk * 32 + quad * 8]);
#pragma unroll
    for (int ct = 0; ct < 8; ct++) {
      short8 bv = *(const short8*)(&Bs[ct * 16 + m16][kk * 32 + quad * 8]);
      acc[ct] = __builtin_amdgcn_mfma_f32_16x16x32_bf16(av, bv, acc[ct], 0, 0, 0);
    }
  }
  __syncthreads();
  // epilogue: C/D layout col=lane&15, row=quad*4+reg -> LDS bounce -> 16B stores
#pragma unroll
  for (int ct = 0; ct < 8; ct++) {
#pragma unroll
    for (int r = 0; r < 4; r++) {
      As[w * 16 + quad * 4 + r][ct * 16 + m16] = f2bf(acc[ct][r]);
    }
  }
  __syncthreads();
#pragma unroll
  for (int pass = 0; pass < 4; pass++) {
    int r = pass * 16 + rs;
    int gr = row0 + r;
    if (gr < NN) *(uint4*)(Y + (size_t)gr * yst + c * 8) = *(const uint4*)(&As[r][c * 8]);
  }
}

__device__ __forceinline__ f32x2 bf2x2(u32 v) {
  f32x2 r;
  r.x = __uint_as_float(v << 16);
  r.y = __uint_as_float(v & 0xffff0000u);
  return r;
}

// packed float2 FMA payload (targets v_pk_fma_f32)
__device__ __forceinline__ void fma8p(f32x2* a, uint4 v, float cf) {
  f32x2 c2; c2.x = cf; c2.y = cf;
  a[0] += c2 * bf2x2(v.x);
  a[1] += c2 * bf2x2(v.y);
  a[2] += c2 * bf2x2(v.z);
  a[3] += c2 * bf2x2(v.w);
}

// self term + bias, pack -> Xo (no stats here: per-element global atomics are
// ~100x more expensive than per-block-reduced work on MI355X — round 7 lesson)
__device__ __forceinline__ void fin_chain(const float* a, const u16* Yb, int st, int node,
                                          int fo, float d2, const float* bias,
                                          u16* __restrict__ Xo) {
  uint4 sv = *(const uint4*)(Yb + (size_t)node * st + fo);
  float s[8] = {
    __uint_as_float(sv.x << 16), __uint_as_float(sv.x & 0xffff0000u),
    __uint_as_float(sv.y << 16), __uint_as_float(sv.y & 0xffff0000u),
    __uint_as_float(sv.z << 16), __uint_as_float(sv.z & 0xffff0000u),
    __uint_as_float(sv.w << 16), __uint_as_float(sv.w & 0xffff0000u)};
  float4 b0 = *(const float4*)(bias + fo);
  float4 b1 = *(const float4*)(bias + fo + 4);
  float bb[8] = {b0.x, b0.y, b0.z, b0.w, b1.x, b1.y, b1.z, b1.w};
  float o[8];
#pragma unroll
  for (int j = 0; j < 8; j++) o[j] = a[j] + d2 * s[j] + bb[j];
  uint4 ou;
  u32* op = (u32*)&ou;
#pragma unroll
  for (int j = 0; j < 4; j++)
    op[j] = (u32)f2bf(o[2 * j]) | ((u32)f2bf(o[2 * j + 1]) << 16);
  *(uint4*)(Xo + (size_t)node * NH + fo) = ou;
}

// GCN aggregate, compacted 1-D grid (8750 blocks) — round-12 measured optimum.
// Refuted levers (record): r14 4x unroll (VGPR cliff), r16 sub-line feature
// chunking (2x line traffic), r13 chain steering (null), r17 nt-hint (null),
// r19 ent prefetch (null). r21: dual path maps node via degree-DESCENDING perm
// (LPT schedule) — heavy nodes start first, dispatch tail is lightest work.
// Per-node work and accumulation order unchanged -> bit-identical.
//   blocks 0..4999: chains 0&4 FUSED on interleaved ydual (shared entry loads +
//     addr math), 4 nodes/block (wave each), 4 edge-groups x 16 lanes,
//     2x unroll + shuffle reduce, ent prefetch pipeline.
//   blocks 5000..8749: MST chain 1..3 (avg deg~2), 16 nodes/block:
//     one 16-lane group per node, 2x-unrolled pair loop, no shuffles.
__global__ __launch_bounds__(256) void k_agg2(ZP p, const int* __restrict__ indptr,
                                              const u32* __restrict__ ent,
                                              const float* __restrict__ dinv, int4 entoff,
                                              const int* __restrict__ perm) {
  int b = blockIdx.x;
  int wv = threadIdx.x >> 6, lane = threadIdx.x & 63;
  int g = lane >> 4;
  int fo = (lane & 15) * 8;
  if (b < 5000) {
    int node = perm[b * 4 + wv];  // degree-descending schedule (r21)
    // dual: chains 0 and 4 interleaved in ydual (stride 256; Y4 = Y0 + 128)
    int beg = indptr[node], end = indptr[node + 1];
    const u16* __restrict__ Y0 = p.Y[0];
    const u16* __restrict__ Y4 = p.Y[4];
    int st = p.ystride[0];
    f32x2 a0[4], a4[4];
#pragma unroll
    for (int j = 0; j < 4; j++) { a0[j] = (f32x2)(0.f); a4[j] = (f32x2)(0.f); }
    int e = beg + g;
    if (e + 4 < end) {
      u32 sa = __builtin_nontemporal_load(ent + e);
      u32 sb = __builtin_nontemporal_load(ent + e + 4);
      while (e + 4 < end) {
        u32 na = __builtin_nontemporal_load(ent + e + 8);
        u32 nb = __builtin_nontemporal_load(ent + e + 12);
        size_t ra = (size_t)(sa & 0xffffu) * st + fo;
        size_t rb = (size_t)(sb & 0xffffu) * st + fo;
        uint4 va0 = *(const uint4*)(Y0 + ra);
        uint4 va4 = *(const uint4*)(Y4 + ra);
        uint4 vb0 = *(const uint4*)(Y0 + rb);
        uint4 vb4 = *(const uint4*)(Y4 + rb);
        float ca = __uint_as_float(sa & 0xffff0000u);
        float cb = __uint_as_float(sb & 0xffff0000u);
        fma8p(a0, va0, ca); fma8p(a4, va4, ca);
        fma8p(a0, vb0, cb); fma8p(a4, vb4, cb);
        e += 8;
        sa = na; sb = nb;
      }
    }
    if (e < end) {
      u32 sc = __builtin_nontemporal_load(ent + e);
      float cf = __uint_as_float(sc & 0xffff0000u);
      size_t ro = (size_t)(sc & 0xffffu) * st + fo;
      uint4 v0 = *(const uint4*)(Y0 + ro);
      uint4 v4 = *(const uint4*)(Y4 + ro);
      fma8p(a0, v0, cf);
      fma8p(a4, v4, cf);
    }
    float* f0 = (float*)a0;
    float* f4 = (float*)a4;
#pragma unroll
    for (int j = 0; j < 8; j++) {
      f0[j] += __shfl_xor(f0[j], 16);
      f0[j] += __shfl_xor(f0[j], 32);
      f4[j] += __shfl_xor(f4[j], 16);
      f4[j] += __shfl_xor(f4[j], 32);
    }
    if (g == 0) {
      float di = dinv[node];
      float d2 = di * di;
      fin_chain(f0, Y0, st, node, fo, d2, p.bias[0], p.Xo[0]);
      fin_chain(f4, Y4, st, node, fo, d2, p.bias[4], p.Xo[4]);
    }
  } else {
    int mb = b - 5000;
    int s = 1 + mb / 1250;       // chain == edge set, 1..3
    int node = (mb % 1250) * 16 + wv * 4 + g;  // 1250*16 == NN exactly
    const int* ip = indptr + s * (NN + 1);
    int eb = (s == 1) ? entoff.y : ((s == 2) ? entoff.z : entoff.w);
    const u16* __restrict__ Y = p.Y[s];
    int st = p.ystride[s];
    int beg = ip[node], end = ip[node + 1];
    const u32* __restrict__ ev = ent + eb;
    f32x2 a[4];
#pragma unroll
    for (int j = 0; j < 4; j++) a[j] = (f32x2)(0.f);
    int e = beg;
    for (; e + 1 < end; e += 2) {
      u32 s0 = ev[e];      // same addr across the 16-lane group -> one fetch
      u32 s1 = ev[e + 1];
      uint4 v0 = *(const uint4*)(Y + (size_t)(s0 & 0xffffu) * st + fo);
      uint4 v1 = *(const uint4*)(Y + (size_t)(s1 & 0xffffu) * st + fo);
      fma8p(a, v0, __uint_as_float(s0 & 0xffff0000u));
      fma8p(a, v1, __uint_as_float(s1 & 0xffff0000u));
    }
    if (e < end) {
      u32 sc = ev[e];
      uint4 v = *(const uint4*)(Y + (size_t)(sc & 0xffffu) * st + fo);
      fma8p(a, v, __uint_as_float(sc & 0xffff0000u));
    }
    float di = dinv[s * NN + node];
    float d2 = di * di;
    fin_chain((float*)a, Y, st, node, fo, d2, p.bias[s], p.Xo[s]);
  }
}

// fused graph-norm: grid (NG, NCH, 4 feature-chunks), 256 thr = 16 feature-pairs
// x 16 row-streams — measured optimum (r18's 64-feature+LDS-cache variant cost
// 21 µs: fewer blocks + 47 KB LDS dropped occupancy while pass-2 reads were
// L2-hot anyway; parallelism > re-read elimination here). Two passes over the
// graph's contiguous row slab (batch is sorted): stats via LDS tree (zero
// atomics), then leaky+M-sum. No Xn store (r15) — affine {mm, inv} goes to aff
// for the next layer's fused GEMM staging.
__global__ __launch_bounds__(256) void k_norm2(ZP p, const int* __restrict__ gstart,
                                               const int* __restrict__ counts,
                                               float* __restrict__ Ml,
                                               float* __restrict__ aff) {
  int g = blockIdx.x, zi = blockIdx.y, fc = blockIdx.z;
  const u16* __restrict__ X = p.Xo[zi];
  int t = threadIdx.x;
  int fj = t & 15;
  int f2 = fc * 32 + fj * 2;
  int rh = t >> 4;  // 16 row streams
  int start = gstart[g], cnt = counts[g];
  __shared__ float red[4][16][17];
  float s0 = 0.f, s1 = 0.f, q0 = 0.f, q1 = 0.f;
  for (int i = rh; i < cnt; i += 16) {
    u32 v = *(const u32*)(X + (size_t)(start + i) * NH + f2);
    float v0 = __uint_as_float(v << 16), v1 = __uint_as_float(v & 0xffff0000u);
    s0 += v0; q0 += v0 * v0;
    s1 += v1; q1 += v1 * v1;
  }
  red[0][rh][fj] = s0; red[1][rh][fj] = s1;
  red[2][rh][fj] = q0; red[3][rh][fj] = q1;
  __syncthreads();
#pragma unroll
  for (int off = 8; off >= 1; off >>= 1) {
    if (rh < off) {
      red[0][rh][fj] += red[0][rh + off][fj];
      red[1][rh][fj] += red[1][rh + off][fj];
      red[2][rh][fj] += red[2][rh + off][fj];
      red[3][rh][fj] += red[3][rh + off][fj];
    }
    __syncthreads();
  }
  float cntf = fmaxf((float)cnt, 1.f);
  float w0 = p.gw[zi][f2], w1 = p.gw[zi][f2 + 1];
  float b0 = p.gb[zi][f2], b1 = p.gb[zi][f2 + 1];
  float ms0 = p.gms[zi][f2], ms1 = p.gms[zi][f2 + 1];
  float mean0 = red[0][0][fj] / cntf, mean1 = red[1][0][fj] / cntf;
  float mm0 = ms0 * mean0, mm1 = ms1 * mean1;
  float var0 = red[2][0][fj] / cntf - (2.f * ms0 - ms0 * ms0) * mean0 * mean0;
  float var1 = red[3][0][fj] / cntf - (2.f * ms1 - ms1 * ms1) * mean1 * mean1;
  float inv0 = rsqrtf(var0 + GEPS), inv1 = rsqrtf(var1 + GEPS);
  __syncthreads();  // all reads of red done before reuse
  float m0 = 0.f, m1 = 0.f;
  for (int i = rh; i < cnt; i += 16) {
    size_t ro = (size_t)(start + i) * NH + f2;
    u32 v = *(const u32*)(X + ro);
    float v0 = __uint_as_float(v << 16), v1 = __uint_as_float(v & 0xffff0000u);
    float o0 = w0 * (v0 - mm0) * inv0 + b0;
    float o1 = w1 * (v1 - mm1) * inv1 + b1;
    o0 = (o0 >= 0.f) ? o0 : GSLOPE * o0;
    o1 = (o1 >= 0.f) ? o1 : GSLOPE * o1;
    m0 += o0; m1 += o1;
  }
  red[0][rh][fj] = m0; red[1][rh][fj] = m1;
  __syncthreads();
#pragma unroll
  for (int off = 8; off >= 1; off >>= 1) {
    if (rh < off) {
      red[0][rh][fj] += red[0][rh + off][fj];
      red[1][rh][fj] += red[1][rh + off][fj];
    }
    __syncthreads();
  }
  if (rh == 0) {
    int col = p.colbase[zi] + f2;
    Ml[(size_t)g * 640 + col] = red[0][0][fj];
    Ml[(size_t)g * 640 + col + 1] = red[1][0][fj];
    if (aff) {
      float* ab = aff + ((size_t)zi * NG + g) * 2 * NH;
      ab[f2] = mm0; ab[f2 + 1] = mm1;
      ab[NH + f2] = inv0; ab[NH + f2 + 1] = inv1;
    }
  }
}

// out[g][f] = mean_l(M[l][g][:] @ mergeW[:,f]) / cnt + mergeb[f]
__global__ __launch_bounds__(256) void k_mergeout(const float* __restrict__ M,
                                                  const float* __restrict__ mergeW,
                                                  const float* __restrict__ mergeb,
                                                  const int* __restrict__ counts,
                                                  float* __restrict__ out) {
  int g = blockIdx.x;
  int f = threadIdx.x & 127, h = threadIdx.x >> 7;
  __shared__ float mrow[640];
  __shared__ float red[128];
  float acc = 0.f;
  for (int l = 0; l < NLAY; l++) {
    const float* Mr = M + ((size_t)l * NG + g) * 640;
    for (int i = threadIdx.x; i < 640; i += 256) mrow[i] = Mr[i];
    __syncthreads();
    float s = 0.f;
    int k0 = h * 320;
#pragma unroll 8
    for (int k = k0; k < k0 + 320; k++) s += mrow[k] * mergeW[(size_t)k * NH + f];
    if (h) red[f] = s;
    __syncthreads();
    if (!h) acc += s + red[f];
    __syncthreads();
  }
  if (!h) {
    float cnt = fmaxf((float)counts[g], 1.f);
    out[(size_t)g * NH + f] = acc / (3.f * cnt) + mergeb[f];
  }
}

// ---------------- host ----------------

struct Offs {
  size_t counts, gstart, deg, dbins, M, dinv, indptr, cursor, ent, wt, ydual, aff, tscan, perm;
  size_t yb[NCH], xo[NCH];
  size_t memset1_off, memset1_len, total;
};

static size_t build_offs(Offs& o, int Etot) {
  size_t off = 0;
  auto alloc = [&](size_t bytes) -> size_t {
    off = (off + 255) & ~(size_t)255;
    size_t s = off;
    off += bytes;
    return s;
  };
  o.counts = alloc(NG * 4);
  o.gstart = alloc(NG * 4);
  o.deg = alloc((size_t)4 * NN * 4);   // 320000 B (multiple of 256)
  o.dbins = alloc((size_t)512 * 4);    // bins[256] + binoff[256], contiguous w/ deg
  o.memset1_off = o.deg;
  o.memset1_len = (size_t)4 * NN * 4 + 512 * 4;  // deg + bins zeroed together
  o.M = alloc((size_t)NLAY * NG * 640 * 4);  // fully overwritten by k_norm2
  o.dinv = alloc((size_t)4 * NN * 4);
  o.indptr = alloc((size_t)4 * (NN + 1) * 4);
  o.cursor = alloc((size_t)4 * (NN + 1) * 4);
  o.ent = alloc((size_t)Etot * 4);  // packed 4B entries
  o.wt = alloc((size_t)7 * NH * NH * 2);
  o.aff = alloc((size_t)NCH * NG * 2 * NH * 4);  // {mm, inv} per (chain, graph)
  o.tscan = alloc((size_t)160 * 4);  // tile sums [4][20] + tile offsets [4][20]
  o.perm = alloc((size_t)NN * 4);    // degree-descending node permutation
  o.ydual = alloc((size_t)NN * 256 * 2);  // chains 0&4 interleaved
  for (int i = 1; i < 4; i++) o.yb[i] = alloc((size_t)NN * NH * 2);
  for (int i = 0; i < NCH; i++) {
    o.xo[i] = alloc((size_t)NNP * NH * 2);  // padded: fused gemm staging reads past NN
  }
  o.total = off;
  return off;
}

extern "C" void kernel_launch(void* const* d_in, const int* in_sizes, int n_in,
                              void* d_out, int out_size, void* d_ws, size_t ws_size,
                              hipStream_t stream) {
  if (n_in < 21) return;
  const float* x = (const float*)d_in[0];
  const float* embW = (const float*)d_in[1];
  const float* embb = (const float*)d_in[2];
  const float* mainW = (const float*)d_in[3];
  const float* mainb = (const float*)d_in[4];
  const float* maingw = (const float*)d_in[5];
  const float* maingb = (const float*)d_in[6];
  const float* maingms = (const float*)d_in[7];
  const float* locW = (const float*)d_in[8];
  const float* locb = (const float*)d_in[9];
  const float* locgw = (const float*)d_in[10];
  const float* locgb = (const float*)d_in[11];
  const float* locgms = (const float*)d_in[12];
  const float* mergeW = (const float*)d_in[13];
  const float* mergeb = (const float*)d_in[14];
  const int* edge_index = (const int*)d_in[15];
  // d_in[16] = edges0: permutation of edge_index under segment_sum -> reuse set 0
  const int* edges1 = (const int*)d_in[17];
  const int* edges2 = (const int*)d_in[18];
  const int* edges3 = (const int*)d_in[19];
  const int* batch = (const int*)d_in[20];

  int E0 = in_sizes[15] / 2;
  int E1 = in_sizes[17] / 2, E2 = in_sizes[18] / 2, E3 = in_sizes[19] / 2;
  int Etot = E0 + E1 + E2 + E3;
  int maxE = E0 > E1 ? E0 : E1;
  maxE = maxE > E2 ? maxE : E2;
  maxE = maxE > E3 ? maxE : E3;

  Offs o;
  if (build_offs(o, Etot) > ws_size) return;  // fail visibly

  char* ws = (char*)d_ws;
  int* counts = (int*)(ws + o.counts);
  int* gstart = (int*)(ws + o.gstart);
  int* deg = (int*)(ws + o.deg);
  int* dbins = (int*)(ws + o.dbins);       // bins[0..255], binoff[256..511]
  float* M = (float*)(ws + o.M);
  float* dinv = (float*)(ws + o.dinv);
  int* indptr = (int*)(ws + o.indptr);
  int* cursor = (int*)(ws + o.cursor);
  u32* ent = (u32*)(ws + o.ent);
  u16* wt = (u16*)(ws + o.wt);
  float* aff = (float*)(ws + o.aff);
  int* tscan = (int*)(ws + o.tscan);
  int* perm = (int*)(ws + o.perm);
  u16* ydual = (u16*)(ws + o.ydual);
  u16 *yb[NCH], *xo[NCH];
  for (int i = 1; i < 4; i++) yb[i] = (u16*)(ws + o.yb[i]);
  for (int i = 0; i < NCH; i++) xo[i] = (u16*)(ws + o.xo[i]);

  ES4 es;
  es.e[0] = edge_index; es.e[1] = edges1; es.e[2] = edges2; es.e[3] = edges3;
  es.cnt[0] = E0; es.cnt[1] = E1; es.cnt[2] = E2; es.cnt[3] = E3;
  es.off[0] = 0; es.off[1] = E0; es.off[2] = E0 + E1; es.off[3] = E0 + E1 + E2;
  int4 entoff = make_int4(0, E0, E0 + E1, E0 + E1 + E2);

  hipMemsetAsync(ws + o.memset1_off, 0, o.memset1_len, stream);  // deg + bins
  k_setup<<<dim3((maxE + 255) / 256, 11), 256, 0, stream>>>(es, deg, embW, locW, mainW, wt);
  k_scanA<<<dim3(20, 4), 1024, 0, stream>>>(deg, indptr, dinv, tscan, dbins);
  k_scanB<<<1, 128, 0, stream>>>(tscan, tscan + 80, indptr, cursor, batch, counts, gstart,
                                 dbins, dbins + 256);
  k_scanC<<<dim3(20, 4), 1024, 0, stream>>>(indptr, cursor, tscan + 80, deg,
                                            dbins + 256, perm);
  k_fill<<<dim3((maxE + 255) / 256, 4), 256, 0, stream>>>(es, dinv, cursor, ent);

  const int nrb = (NN + 63) / 64;  // 313

  // fused embedding + layer-0 GEMMs -> ydual (both halves)
  k_gemm0<<<nrb, 256, 0, stream>>>(x, wt, embb, ydual);

  for (int l = 0; l < NLAY; l++) {
    int lp = (l > 0) ? (l - 1) : 0;  // previous layer's norm params (unused at l=0)
    ZP p = {};
    for (int zi = 0; zi < NCH; zi++) {
      bool isMain = (zi == 4);
      p.A[zi] = (const u16*)xo[zi];  // fused staging source: pre-norm of layer l-1
      p.W[zi] = wt + (size_t)((isMain ? 4 : 1) + l) * NH * NH;
      if (zi == 0) { p.Y[0] = ydual; p.ystride[0] = 256; }
      else if (zi == 4) { p.Y[4] = ydual + 128; p.ystride[4] = 256; }
      else { p.Y[zi] = yb[zi]; p.ystride[zi] = 128; }
      p.Xo[zi] = xo[zi];
      p.bias[zi] = (isMain ? mainb : locb) + (size_t)l * NH;
      p.gw[zi] = (isMain ? maingw : locgw) + (size_t)l * NH;
      p.gb[zi] = (isMain ? maingb : locgb) + (size_t)l * NH;
      p.gms[zi] = (isMain ? maingms : locgms) + (size_t)l * NH;
      p.pgw[zi] = (isMain ? maingw : locgw) + (size_t)lp * NH;
      p.pgb[zi] = (isMain ? maingb : locgb) + (size_t)lp * NH;
      p.colbase[zi] = isMain ? 512 : zi * NH;
    }
    if (l == 0) {
      // k_gemm0 already produced ydual; MST chains gather from chain-0 half
      p.Y[1] = ydual; p.Y[2] = ydual; p.Y[3] = ydual;
      p.ystride[1] = p.ystride[2] = p.ystride[3] = 256;
    } else {
      k_gemm_bf<<<dim3(nrb, NCH), 256, 0, stream>>>(p, batch, aff);
    }
    k_agg2<<<8750, 256, 0, stream>>>(p, indptr, ent, dinv, entoff, perm);
    k_norm2<<<dim3(NG, NCH, 4), 256, 0, stream>>>(p, gstart, counts,
                                                  M + (size_t)l * NG * 640,
                                                  (l == NLAY - 1) ? nullptr : aff);
  }

  k_mergeout<<<NG, 256, 0, stream>>>(M, mergeW, mergeb, counts, (float*)d_out);
}

// Round 9
// 379.360 us; speedup vs baseline: 1.2613x; 1.2613x over previous
//
#include <hip/hip_runtime.h>

#define NN 20000      // nodes
#define NNP 20032     // padded rows (64-row GEMM tiles read past NN)
#define NH 128        // hidden
#define NG 64         // graphs
#define NLAY 3
#define NCH 5         // 4 splits + main
#define GEPS 1e-5f
#define GSLOPE 0.01f

typedef unsigned short u16;
typedef unsigned int u32;
typedef __attribute__((ext_vector_type(8))) short short8;
typedef __attribute__((ext_vector_type(4))) float float4v;
typedef __attribute__((ext_vector_type(2))) float f32x2;

__device__ __forceinline__ u16 f2bf(float f) {
  union { float f; u32 u; } v; v.f = f;
  u32 r = (v.u + 0x7fffu + ((v.u >> 16) & 1u)) >> 16;
  return (u16)r;
}

struct ZP {
  const u16* A[NCH];     // GEMM input = Xo of previous layer (bf16, NN rows)
  const u16* W[NCH];     // GEMM weight, bf16 transposed [N][K]
  u16* Y[NCH];           // GEMM output / gather source (bf16)
  int ystride[NCH];      // row stride of Y in elements (256 for ydual, 128 else)
  u16* Xo[NCH];          // post-agg pre-norm (bf16, stride NH)
  const float* bias[NCH];
  const float* gw[NCH];  // this layer's norm weight (for k_norm2)
  const float* gb[NCH];
  const float* gms[NCH];
  const float* pgw[NCH]; // PREVIOUS layer's norm weight (for fused gemm staging)
  const float* pgb[NCH];
  int colbase[NCH];
};

struct ES4 {
  const int* e[4];
  int cnt[4];
  int off[4];
};

// ---------------- setup kernels ----------------

// r20: parallel two-phase scan (replaced 5-CU serial scan: −10.6 µs).
// r21: LPT degree-descending perm — but GLOBAL atomic histogram/scatter
//   serialized at L2 (k_scanC 54.6 µs at 0.03% VALU: ~20000 same-line atomics).
// r22: contention-free counting sort — per-tile LDS histograms (scanA),
//   one-block offset combine (scanB), LDS-rank scatter (scanC). Zero global
//   atomics. Per-node work/order unchanged -> bit-identical output.
__global__ __launch_bounds__(1024) void k_scanA(const int* __restrict__ deg,
                                                int* __restrict__ indptr,
                                                float* __restrict__ dinv,
                                                int* __restrict__ tsum,
                                                int* __restrict__ th) {
  int s = blockIdx.y, tile = blockIdx.x;
  int t = threadIdx.x;
  __shared__ int h[256];
  __shared__ int wsum[16];
  if (t < 256) h[t] = 0;
  __syncthreads();
  int idx = tile * 1024 + t;
  int v = 0;
  if (idx < NN) {
    v = deg[s * NN + idx];
    dinv[s * NN + idx] = rsqrtf((float)v + 1.0f);
    if (s == 0) atomicAdd(&h[v < 255 ? v : 255], 1);  // LDS histogram (fast)
  }
  int lane = t & 63, wv = t >> 6;  // 16 waves
  int x = v;
#pragma unroll
  for (int o = 1; o < 64; o <<= 1) {
    int y = __shfl_up(x, o);
    if (lane >= o) x += y;
  }
  if (lane == 63) wsum[wv] = x;
  __syncthreads();
  if (wv == 0) {
    int y = (lane < 16) ? wsum[lane] : 0;
#pragma unroll
    for (int o = 1; o < 16; o <<= 1) {
      int z = __shfl_up(y, o);
      if (lane >= o) y += z;
    }
    if (lane < 16) wsum[lane] = y;
  }
  __syncthreads();
  int waveoff = (wv == 0) ? 0 : wsum[wv - 1];
  int excl = waveoff + x - v;  // exclusive within tile
  if (idx < NN) indptr[s * (NN + 1) + idx] = excl;
  if (t == 1023) tsum[s * 20 + tile] = waveoff + x;  // tile total
  if (s == 0 && t < 256) th[tile * 256 + t] = h[t];  // per-tile histogram out
}

__global__ __launch_bounds__(256) void k_scanB(const int* __restrict__ tsum,
                                               int* __restrict__ toff,
                                               int* __restrict__ indptr,
                                               int* __restrict__ cursor,
                                               const int* __restrict__ batch,
                                               int* __restrict__ counts,
                                               int* __restrict__ gstart,
                                               const int* __restrict__ th,
                                               int* __restrict__ tboff) {
  int t = threadIdx.x;
  __shared__ int tot[256];
  __shared__ int desc[256];
  // per-bin totals across the 20 tiles (thread t owns bin t)
  int s0 = 0;
  for (int i = 0; i < 20; i++) s0 += th[i * 256 + t];
  tot[t] = s0;
  __syncthreads();
  if (t == 0) {  // descending-bin exclusive scan (256 iters, trivial)
    int run = 0;
    for (int b = 255; b >= 0; b--) { desc[b] = run; run += tot[b]; }
  }
  __syncthreads();
  {  // per-(tile,bin) global offsets
    int run = desc[t];
    for (int i = 0; i < 20; i++) { tboff[i * 256 + t] = run; run += th[i * 256 + t]; }
  }
  if (t < 4) {
    int run = 0;
    for (int i = 0; i < 20; i++) {
      toff[t * 20 + i] = run;
      run += tsum[t * 20 + i];
    }
    indptr[t * (NN + 1) + NN] = run;
    cursor[t * (NN + 1) + NN] = run;
  }
  if (t >= 64 && t < 128) {
    int g = t - 64;  // per-graph start/count via binary search (batch sorted)
    auto lb = [&](int key) {
      int lo = 0, hi = NN;
      while (lo < hi) {
        int mid = (lo + hi) >> 1;
        if (batch[mid] < key) lo = mid + 1; else hi = mid;
      }
      return lo;
    };
    int a = lb(g), b = lb(g + 1);
    gstart[g] = a;
    counts[g] = b - a;
  }
}

__global__ __launch_bounds__(1024) void k_scanC(int* __restrict__ indptr,
                                                int* __restrict__ cursor,
                                                const int* __restrict__ toff,
                                                const int* __restrict__ deg,
                                                const int* __restrict__ tboff,
                                                int* __restrict__ perm) {
  int s = blockIdx.y, tile = blockIdx.x;
  int t = threadIdx.x;
  __shared__ int h[256];
  if (t < 256) h[t] = 0;
  __syncthreads();
  int idx = tile * 1024 + t;
  if (idx < NN) {
    int v = indptr[s * (NN + 1) + idx] + toff[s * 20 + tile];
    indptr[s * (NN + 1) + idx] = v;
    cursor[s * (NN + 1) + idx] = v;
    if (s == 0) {  // LDS-rank scatter into degree-descending slot
      int d = deg[idx];
      int bb = d < 255 ? d : 255;
      int r = atomicAdd(&h[bb], 1);
      perm[tboff[tile * 256 + bb] + r] = idx;
    }
  }
}

// packed entry: low 16 = src (NN < 2^16), high 16 = coef as bf16.
__global__ void k_fill(ES4 es, const float* __restrict__ dinv, int* __restrict__ cursor,
                       u32* __restrict__ ent) {
  int s = blockIdx.y;
  int i = blockIdx.x * 256 + threadIdx.x;
  int E = es.cnt[s];
  if (i >= E) return;
  int src = es.e[s][i];
  int dst = es.e[s][E + i];
  int pos = atomicAdd(&cursor[s * (NN + 1) + dst], 1);
  float c = dinv[s * NN + src] * dinv[s * NN + dst];
  ent[es.off[s] + pos] = (u32)src | ((u32)f2bf(c) << 16);
}

// fused setup: y<4 -> deg histogram for edge set y; y in 4..10 -> weight transpose
// fp32[K][N]->bf16[N][K] for mat y-4 (x<16).
__global__ __launch_bounds__(256) void k_setup(ES4 es, int* __restrict__ deg,
                                               const float* __restrict__ embW,
                                               const float* __restrict__ locW,
                                               const float* __restrict__ mainW,
                                               u16* __restrict__ wt) {
  int ybk = blockIdx.y;
  if (ybk < 4) {
    int s = ybk;
    int i = blockIdx.x * 256 + threadIdx.x;
    int E = es.cnt[s];
    if (i < E) atomicAdd(&deg[s * NN + es.e[s][E + i]], 1);
    return;
  }
  if (blockIdx.x >= 16) return;
  int mat = ybk - 4;
  const float* W = (mat == 0) ? embW : ((mat <= 3) ? locW + (mat - 1) * NH * NH
                                                   : mainW + (mat - 4) * NH * NH);
  int tile = blockIdx.x;
  int tk = (tile >> 2) * 32;
  int tn = (tile & 3) * 32;
  __shared__ float tl[32][33];
  int c = threadIdx.x & 31, r = threadIdx.x >> 5;
#pragma unroll
  for (int rr = 0; rr < 32; rr += 8)
    tl[r + rr][c] = W[(size_t)(tk + r + rr) * NH + tn + c];
  __syncthreads();
#pragma unroll
  for (int rr = 0; rr < 32; rr += 8)
    wt[(size_t)mat * NH * NH + (size_t)(tn + r + rr) * NH + tk + c] = f2bf(tl[c][r + rr]);
}

// ---------------- compute kernels ----------------

// Fused embedding + layer-0 GEMMs: per 64-row tile,
//   h = bf16(x) @ embW + embb       (h lives only in LDS, bf16)
//   ydual[:,0:128]   = h @ locW0    (shared by split chains 0..3)
//   ydual[:,128:256] = h @ mainW0
__global__ __launch_bounds__(256) void k_gemm0(const float* __restrict__ x,
                                               const u16* __restrict__ wt,
                                               const float* __restrict__ embb,
                                               u16* __restrict__ ydual) {
  __shared__ u16 As[64][136];
  __shared__ u16 Bs[128][136];
  int t = threadIdx.x;
  int row0 = blockIdx.x * 64;
  int c = t & 15, rs = t >> 4;
#pragma unroll
  for (int pass = 0; pass < 4; pass++) {
    int r = pass * 16 + rs;
    int gr = row0 + r;
    uint4 o = make_uint4(0, 0, 0, 0);
    if (gr < NN) {
      float4 a = *(const float4*)(x + (size_t)gr * NH + c * 8);
      float4 b = *(const float4*)(x + (size_t)gr * NH + c * 8 + 4);
      o.x = f2bf(a.x) | ((u32)f2bf(a.y) << 16);
      o.y = f2bf(a.z) | ((u32)f2bf(a.w) << 16);
      o.z = f2bf(b.x) | ((u32)f2bf(b.y) << 16);
      o.w = f2bf(b.z) | ((u32)f2bf(b.w) << 16);
    }
    *(uint4*)(&As[r][c * 8]) = o;
  }
#pragma unroll
  for (int pass = 0; pass < 8; pass++) {
    int n = pass * 16 + rs;
    *(uint4*)(&Bs[n][c * 8]) = *(const uint4*)(wt + (size_t)n * NH + c * 8);  // embW
  }
  __syncthreads();
  int lane = t & 63, w = t >> 6;
  int m16 = lane & 15, quad = lane >> 4;
  float4v acc[8];
#pragma unroll
  for (int i = 0; i < 8; i++) acc[i] = (float4v)(0.f);
#pragma unroll
  for (int kk = 0; kk < 4; kk++) {
    short8 av = *(const short8*)(&As[w * 16 + m16][kk * 32 + quad * 8]);
#pragma unroll
    for (int ct = 0; ct < 8; ct++) {
      short8 bv = *(const short8*)(&Bs[ct * 16 + m16][kk * 32 + quad * 8]);
      acc[ct] = __builtin_amdgcn_mfma_f32_16x16x32_bf16(av, bv, acc[ct], 0, 0, 0);
    }
  }
  __syncthreads();  // stage-1 LDS reads complete
#pragma unroll
  for (int ct = 0; ct < 8; ct++) {
    float bv = embb[ct * 16 + m16];
#pragma unroll
    for (int r = 0; r < 4; r++)
      As[w * 16 + quad * 4 + r][ct * 16 + m16] = f2bf(acc[ct][r] + bv);
  }
  {
    const u16* wl = wt + (size_t)1 * NH * NH;  // locW0
#pragma unroll
    for (int pass = 0; pass < 8; pass++) {
      int n = pass * 16 + rs;
      *(uint4*)(&Bs[n][c * 8]) = *(const uint4*)(wl + (size_t)n * NH + c * 8);
    }
  }
  __syncthreads();
  float4v acc0[8];
#pragma unroll
  for (int i = 0; i < 8; i++) acc0[i] = (float4v)(0.f);
#pragma unroll
  for (int kk = 0; kk < 4; kk++) {
    short8 av = *(const short8*)(&As[w * 16 + m16][kk * 32 + quad * 8]);
#pragma unroll
    for (int ct = 0; ct < 8; ct++) {
      short8 bv = *(const short8*)(&Bs[ct * 16 + m16][kk * 32 + quad * 8]);
      acc0[ct] = __builtin_amdgcn_mfma_f32_16x16x32_bf16(av, bv, acc0[ct], 0, 0, 0);
    }
  }
  __syncthreads();  // stage-2 Bs reads complete
  {
    const u16* wm = wt + (size_t)4 * NH * NH;  // mainW0
#pragma unroll
    for (int pass = 0; pass < 8; pass++) {
      int n = pass * 16 + rs;
      *(uint4*)(&Bs[n][c * 8]) = *(const uint4*)(wm + (size_t)n * NH + c * 8);
    }
  }
  __syncthreads();
  float4v acc4[8];
#pragma unroll
  for (int i = 0; i < 8; i++) acc4[i] = (float4v)(0.f);
#pragma unroll
  for (int kk = 0; kk < 4; kk++) {
    short8 av = *(const short8*)(&As[w * 16 + m16][kk * 32 + quad * 8]);
#pragma unroll
    for (int ct = 0; ct < 8; ct++) {
      short8 bv = *(const short8*)(&Bs[ct * 16 + m16][kk * 32 + quad * 8]);
      acc4[ct] = __builtin_amdgcn_mfma_f32_16x16x32_bf16(av, bv, acc4[ct], 0, 0, 0);
    }
  }
  __syncthreads();  // stage-3 LDS reads complete; As/Bs free for bounce
#pragma unroll
  for (int ct = 0; ct < 8; ct++) {
#pragma unroll
    for (int r = 0; r < 4; r++) {
      As[w * 16 + quad * 4 + r][ct * 16 + m16] = f2bf(acc0[ct][r]);
      Bs[w * 16 + quad * 4 + r][ct * 16 + m16] = f2bf(acc4[ct][r]);
    }
  }
  __syncthreads();
#pragma unroll
  for (int pass = 0; pass < 4; pass++) {
    int r = pass * 16 + rs;
    int gr = row0 + r;
    if (gr < NN) {
      *(uint4*)(ydual + (size_t)gr * 256 + c * 8) = *(const uint4*)(&As[r][c * 8]);
      *(uint4*)(ydual + (size_t)gr * 256 + 128 + c * 8) = *(const uint4*)(&Bs[r][c * 8]);
    }
  }
}

// Y[z] = norm_affine(Xo_prev[z]) @ Wt[z]^T. The previous layer's graph-norm +
// leaky is applied during A-staging from per-(chain,graph) {mm=ms*mean, inv}
// (aff buffer) + layer params (pgw/pgb). Expression shape matches k_norm2's old
// Xn path exactly -> bf16-rounded A operand is bit-identical (r15 fusion:
// removes the 102 MB Xn write+read round trip).
__global__ __launch_bounds__(256) void k_gemm_bf(ZP p, const int* __restrict__ batch,
                                                 const float* __restrict__ aff) {
  int zi = blockIdx.y;
  const u16* __restrict__ X = p.A[zi];
  const u16* __restrict__ Wt = p.W[zi];
  u16* __restrict__ Y = p.Y[zi];
  const float* __restrict__ gw = p.pgw[zi];
  const float* __restrict__ gb = p.pgb[zi];
  int yst = p.ystride[zi];
  __shared__ u16 As[64][136];   // +8 pad: 2-way bank aliasing only
  __shared__ u16 Bs[128][136];
  int t = threadIdx.x;
  int row0 = blockIdx.x * 64;
  int c = t & 15, rs = t >> 4;
  float4 wA = *(const float4*)(gw + c * 8);
  float4 wB = *(const float4*)(gw + c * 8 + 4);
  float4 bA = *(const float4*)(gb + c * 8);
  float4 bB = *(const float4*)(gb + c * 8 + 4);
  float wv8[8] = {wA.x, wA.y, wA.z, wA.w, wB.x, wB.y, wB.z, wB.w};
  float bv8[8] = {bA.x, bA.y, bA.z, bA.w, bB.x, bB.y, bB.z, bB.w};
#pragma unroll
  for (int pass = 0; pass < 4; pass++) {
    int r = pass * 16 + rs;
    int gr = row0 + r;
    int grc = (gr < NN) ? gr : (NN - 1);  // clamp: stores are guarded anyway
    int gg = batch[grc];
    const float* ab = aff + ((size_t)zi * NG + gg) * 2 * NH;
    uint4 xv = *(const uint4*)(X + (size_t)grc * NH + c * 8);
    float4 mA = *(const float4*)(ab + c * 8);
    float4 mB = *(const float4*)(ab + c * 8 + 4);
    float4 iA = *(const float4*)(ab + NH + c * 8);
    float4 iB = *(const float4*)(ab + NH + c * 8 + 4);
    float mm[8] = {mA.x, mA.y, mA.z, mA.w, mB.x, mB.y, mB.z, mB.w};
    float iv[8] = {iA.x, iA.y, iA.z, iA.w, iB.x, iB.y, iB.z, iB.w};
    u32 xw[4] = {xv.x, xv.y, xv.z, xv.w};
    uint4 ou;
    u32* op = (u32*)&ou;
#pragma unroll
    for (int j = 0; j < 4; j++) {
      float v0 = __uint_as_float(xw[j] << 16);
      float v1 = __uint_as_float(xw[j] & 0xffff0000u);
      float o0 = wv8[2 * j] * (v0 - mm[2 * j]) * iv[2 * j] + bv8[2 * j];
      float o1 = wv8[2 * j + 1] * (v1 - mm[2 * j + 1]) * iv[2 * j + 1] + bv8[2 * j + 1];
      o0 = (o0 >= 0.f) ? o0 : GSLOPE * o0;
      o1 = (o1 >= 0.f) ? o1 : GSLOPE * o1;
      op[j] = (u32)f2bf(o0) | ((u32)f2bf(o1) << 16);
    }
    *(uint4*)(&As[r][c * 8]) = ou;
  }
#pragma unroll
  for (int pass = 0; pass < 8; pass++) {
    int n = pass * 16 + rs;
    *(uint4*)(&Bs[n][c * 8]) = *(const uint4*)(Wt + (size_t)n * NH + c * 8);
  }
  __syncthreads();
  int lane = t & 63, w = t >> 6;
  int m16 = lane & 15, quad = lane >> 4;
  float4v acc[8];
#pragma unroll
  for (int i = 0; i < 8; i++) acc[i] = (float4v)(0.f);
#pragma unroll
  for (int kk = 0; kk < 4; kk++) {
    short8 av = *(const short8*)(&As[w * 16 + m16][kk * 32 + quad * 8]);
#pragma unroll
    for (int ct = 0; ct < 8; ct++) {
      short8 bv = *(const short8*)(&Bs[ct * 16 + m16][kk * 32 + quad * 8]);
      acc[ct] = __builtin_amdgcn_mfma_f32_16x16x32_bf16(av, bv, acc[ct], 0, 0, 0);
    }
  }
  __syncthreads();
  // epilogue: C/D layout col=lane&15, row=quad*4+reg -> LDS bounce -> 16B stores
#pragma unroll
  for (int ct = 0; ct < 8; ct++) {
#pragma unroll
    for (int r = 0; r < 4; r++) {
      As[w * 16 + quad * 4 + r][ct * 16 + m16] = f2bf(acc[ct][r]);
    }
  }
  __syncthreads();
#pragma unroll
  for (int pass = 0; pass < 4; pass++) {
    int r = pass * 16 + rs;
    int gr = row0 + r;
    if (gr < NN) *(uint4*)(Y + (size_t)gr * yst + c * 8) = *(const uint4*)(&As[r][c * 8]);
  }
}

__device__ __forceinline__ f32x2 bf2x2(u32 v) {
  f32x2 r;
  r.x = __uint_as_float(v << 16);
  r.y = __uint_as_float(v & 0xffff0000u);
  return r;
}

// packed float2 FMA payload (targets v_pk_fma_f32)
__device__ __forceinline__ void fma8p(f32x2* a, uint4 v, float cf) {
  f32x2 c2; c2.x = cf; c2.y = cf;
  a[0] += c2 * bf2x2(v.x);
  a[1] += c2 * bf2x2(v.y);
  a[2] += c2 * bf2x2(v.z);
  a[3] += c2 * bf2x2(v.w);
}

// self term + bias, pack -> Xo (no stats here: per-element global atomics are
// ~100x more expensive than per-block-reduced work on MI355X — round 7 lesson,
// re-confirmed r21 with the contended perm scatter)
__device__ __forceinline__ void fin_chain(const float* a, const u16* Yb, int st, int node,
                                          int fo, float d2, const float* bias,
                                          u16* __restrict__ Xo) {
  uint4 sv = *(const uint4*)(Yb + (size_t)node * st + fo);
  float s[8] = {
    __uint_as_float(sv.x << 16), __uint_as_float(sv.x & 0xffff0000u),
    __uint_as_float(sv.y << 16), __uint_as_float(sv.y & 0xffff0000u),
    __uint_as_float(sv.z << 16), __uint_as_float(sv.z & 0xffff0000u),
    __uint_as_float(sv.w << 16), __uint_as_float(sv.w & 0xffff0000u)};
  float4 b0 = *(const float4*)(bias + fo);
  float4 b1 = *(const float4*)(bias + fo + 4);
  float bb[8] = {b0.x, b0.y, b0.z, b0.w, b1.x, b1.y, b1.z, b1.w};
  float o[8];
#pragma unroll
  for (int j = 0; j < 8; j++) o[j] = a[j] + d2 * s[j] + bb[j];
  uint4 ou;
  u32* op = (u32*)&ou;
#pragma unroll
  for (int j = 0; j < 4; j++)
    op[j] = (u32)f2bf(o[2 * j]) | ((u32)f2bf(o[2 * j + 1]) << 16);
  *(uint4*)(Xo + (size_t)node * NH + fo) = ou;
}

// GCN aggregate, compacted 1-D grid (8750 blocks) — round-12 measured optimum.
// Refuted levers (record): r14 4x unroll (VGPR cliff), r16 sub-line feature
// chunking (2x line traffic), r13 chain steering (null), r17 nt-hint (null),
// r19 ent prefetch (null). r21/r22: dual path maps node via degree-DESCENDING
// perm (LPT schedule) — heavy nodes start first, dispatch tail is lightest.
// Per-node work and accumulation order unchanged -> bit-identical.
//   blocks 0..4999: chains 0&4 FUSED on interleaved ydual (shared entry loads +
//     addr math), 4 nodes/block (wave each), 4 edge-groups x 16 lanes,
//     2x unroll + shuffle reduce, ent prefetch pipeline.
//   blocks 5000..8749: MST chain 1..3 (avg deg~2), 16 nodes/block:
//     one 16-lane group per node, 2x-unrolled pair loop, no shuffles.
__global__ __launch_bounds__(256) void k_agg2(ZP p, const int* __restrict__ indptr,
                                              const u32* __restrict__ ent,
                                              const float* __restrict__ dinv, int4 entoff,
                                              const int* __restrict__ perm) {
  int b = blockIdx.x;
  int wv = threadIdx.x >> 6, lane = threadIdx.x & 63;
  int g = lane >> 4;
  int fo = (lane & 15) * 8;
  if (b < 5000) {
    int node = perm[b * 4 + wv];  // degree-descending schedule (r21)
    // dual: chains 0 and 4 interleaved in ydual (stride 256; Y4 = Y0 + 128)
    int beg = indptr[node], end = indptr[node + 1];
    const u16* __restrict__ Y0 = p.Y[0];
    const u16* __restrict__ Y4 = p.Y[4];
    int st = p.ystride[0];
    f32x2 a0[4], a4[4];
#pragma unroll
    for (int j = 0; j < 4; j++) { a0[j] = (f32x2)(0.f); a4[j] = (f32x2)(0.f); }
    int e = beg + g;
    if (e + 4 < end) {
      u32 sa = __builtin_nontemporal_load(ent + e);
      u32 sb = __builtin_nontemporal_load(ent + e + 4);
      while (e + 4 < end) {
        u32 na = __builtin_nontemporal_load(ent + e + 8);
        u32 nb = __builtin_nontemporal_load(ent + e + 12);
        size_t ra = (size_t)(sa & 0xffffu) * st + fo;
        size_t rb = (size_t)(sb & 0xffffu) * st + fo;
        uint4 va0 = *(const uint4*)(Y0 + ra);
        uint4 va4 = *(const uint4*)(Y4 + ra);
        uint4 vb0 = *(const uint4*)(Y0 + rb);
        uint4 vb4 = *(const uint4*)(Y4 + rb);
        float ca = __uint_as_float(sa & 0xffff0000u);
        float cb = __uint_as_float(sb & 0xffff0000u);
        fma8p(a0, va0, ca); fma8p(a4, va4, ca);
        fma8p(a0, vb0, cb); fma8p(a4, vb4, cb);
        e += 8;
        sa = na; sb = nb;
      }
    }
    if (e < end) {
      u32 sc = __builtin_nontemporal_load(ent + e);
      float cf = __uint_as_float(sc & 0xffff0000u);
      size_t ro = (size_t)(sc & 0xffffu) * st + fo;
      uint4 v0 = *(const uint4*)(Y0 + ro);
      uint4 v4 = *(const uint4*)(Y4 + ro);
      fma8p(a0, v0, cf);
      fma8p(a4, v4, cf);
    }
    float* f0 = (float*)a0;
    float* f4 = (float*)a4;
#pragma unroll
    for (int j = 0; j < 8; j++) {
      f0[j] += __shfl_xor(f0[j], 16);
      f0[j] += __shfl_xor(f0[j], 32);
      f4[j] += __shfl_xor(f4[j], 16);
      f4[j] += __shfl_xor(f4[j], 32);
    }
    if (g == 0) {
      float di = dinv[node];
      float d2 = di * di;
      fin_chain(f0, Y0, st, node, fo, d2, p.bias[0], p.Xo[0]);
      fin_chain(f4, Y4, st, node, fo, d2, p.bias[4], p.Xo[4]);
    }
  } else {
    int mb = b - 5000;
    int s = 1 + mb / 1250;       // chain == edge set, 1..3
    int node = (mb % 1250) * 16 + wv * 4 + g;  // 1250*16 == NN exactly
    const int* ip = indptr + s * (NN + 1);
    int eb = (s == 1) ? entoff.y : ((s == 2) ? entoff.z : entoff.w);
    const u16* __restrict__ Y = p.Y[s];
    int st = p.ystride[s];
    int beg = ip[node], end = ip[node + 1];
    const u32* __restrict__ ev = ent + eb;
    f32x2 a[4];
#pragma unroll
    for (int j = 0; j < 4; j++) a[j] = (f32x2)(0.f);
    int e = beg;
    for (; e + 1 < end; e += 2) {
      u32 s0 = ev[e];      // same addr across the 16-lane group -> one fetch
      u32 s1 = ev[e + 1];
      uint4 v0 = *(const uint4*)(Y + (size_t)(s0 & 0xffffu) * st + fo);
      uint4 v1 = *(const uint4*)(Y + (size_t)(s1 & 0xffffu) * st + fo);
      fma8p(a, v0, __uint_as_float(s0 & 0xffff0000u));
      fma8p(a, v1, __uint_as_float(s1 & 0xffff0000u));
    }
    if (e < end) {
      u32 sc = ev[e];
      uint4 v = *(const uint4*)(Y + (size_t)(sc & 0xffffu) * st + fo);
      fma8p(a, v, __uint_as_float(sc & 0xffff0000u));
    }
    float di = dinv[s * NN + node];
    float d2 = di * di;
    fin_chain((float*)a, Y, st, node, fo, d2, p.bias[s], p.Xo[s]);
  }
}

// fused graph-norm: grid (NG, NCH, 4 feature-chunks), 256 thr = 16 feature-pairs
// x 16 row-streams — measured optimum (r18's 64-feature+LDS-cache variant cost
// 21 µs: fewer blocks + 47 KB LDS dropped occupancy while pass-2 reads were
// L2-hot anyway; parallelism > re-read elimination here). Two passes over the
// graph's contiguous row slab (batch is sorted): stats via LDS tree (zero
// atomics), then leaky+M-sum. No Xn store (r15) — affine {mm, inv} goes to aff
// for the next layer's fused GEMM staging.
__global__ __launch_bounds__(256) void k_norm2(ZP p, const int* __restrict__ gstart,
                                               const int* __restrict__ counts,
                                               float* __restrict__ Ml,
                                               float* __restrict__ aff) {
  int g = blockIdx.x, zi = blockIdx.y, fc = blockIdx.z;
  const u16* __restrict__ X = p.Xo[zi];
  int t = threadIdx.x;
  int fj = t & 15;
  int f2 = fc * 32 + fj * 2;
  int rh = t >> 4;  // 16 row streams
  int start = gstart[g], cnt = counts[g];
  __shared__ float red[4][16][17];
  float s0 = 0.f, s1 = 0.f, q0 = 0.f, q1 = 0.f;
  for (int i = rh; i < cnt; i += 16) {
    u32 v = *(const u32*)(X + (size_t)(start + i) * NH + f2);
    float v0 = __uint_as_float(v << 16), v1 = __uint_as_float(v & 0xffff0000u);
    s0 += v0; q0 += v0 * v0;
    s1 += v1; q1 += v1 * v1;
  }
  red[0][rh][fj] = s0; red[1][rh][fj] = s1;
  red[2][rh][fj] = q0; red[3][rh][fj] = q1;
  __syncthreads();
#pragma unroll
  for (int off = 8; off >= 1; off >>= 1) {
    if (rh < off) {
      red[0][rh][fj] += red[0][rh + off][fj];
      red[1][rh][fj] += red[1][rh + off][fj];
      red[2][rh][fj] += red[2][rh + off][fj];
      red[3][rh][fj] += red[3][rh + off][fj];
    }
    __syncthreads();
  }
  float cntf = fmaxf((float)cnt, 1.f);
  float w0 = p.gw[zi][f2], w1 = p.gw[zi][f2 + 1];
  float b0 = p.gb[zi][f2], b1 = p.gb[zi][f2 + 1];
  float ms0 = p.gms[zi][f2], ms1 = p.gms[zi][f2 + 1];
  float mean0 = red[0][0][fj] / cntf, mean1 = red[1][0][fj] / cntf;
  float mm0 = ms0 * mean0, mm1 = ms1 * mean1;
  float var0 = red[2][0][fj] / cntf - (2.f * ms0 - ms0 * ms0) * mean0 * mean0;
  float var1 = red[3][0][fj] / cntf - (2.f * ms1 - ms1 * ms1) * mean1 * mean1;
  float inv0 = rsqrtf(var0 + GEPS), inv1 = rsqrtf(var1 + GEPS);
  __syncthreads();  // all reads of red done before reuse
  float m0 = 0.f, m1 = 0.f;
  for (int i = rh; i < cnt; i += 16) {
    size_t ro = (size_t)(start + i) * NH + f2;
    u32 v = *(const u32*)(X + ro);
    float v0 = __uint_as_float(v << 16), v1 = __uint_as_float(v & 0xffff0000u);
    float o0 = w0 * (v0 - mm0) * inv0 + b0;
    float o1 = w1 * (v1 - mm1) * inv1 + b1;
    o0 = (o0 >= 0.f) ? o0 : GSLOPE * o0;
    o1 = (o1 >= 0.f) ? o1 : GSLOPE * o1;
    m0 += o0; m1 += o1;
  }
  red[0][rh][fj] = m0; red[1][rh][fj] = m1;
  __syncthreads();
#pragma unroll
  for (int off = 8; off >= 1; off >>= 1) {
    if (rh < off) {
      red[0][rh][fj] += red[0][rh + off][fj];
      red[1][rh][fj] += red[1][rh + off][fj];
    }
    __syncthreads();
  }
  if (rh == 0) {
    int col = p.colbase[zi] + f2;
    Ml[(size_t)g * 640 + col] = red[0][0][fj];
    Ml[(size_t)g * 640 + col + 1] = red[1][0][fj];
    if (aff) {
      float* ab = aff + ((size_t)zi * NG + g) * 2 * NH;
      ab[f2] = mm0; ab[f2 + 1] = mm1;
      ab[NH + f2] = inv0; ab[NH + f2 + 1] = inv1;
    }
  }
}

// out[g][f] = mean_l(M[l][g][:] @ mergeW[:,f]) / cnt + mergeb[f]
__global__ __launch_bounds__(256) void k_mergeout(const float* __restrict__ M,
                                                  const float* __restrict__ mergeW,
                                                  const float* __restrict__ mergeb,
                                                  const int* __restrict__ counts,
                                                  float* __restrict__ out) {
  int g = blockIdx.x;
  int f = threadIdx.x & 127, h = threadIdx.x >> 7;
  __shared__ float mrow[640];
  __shared__ float red[128];
  float acc = 0.f;
  for (int l = 0; l < NLAY; l++) {
    const float* Mr = M + ((size_t)l * NG + g) * 640;
    for (int i = threadIdx.x; i < 640; i += 256) mrow[i] = Mr[i];
    __syncthreads();
    float s = 0.f;
    int k0 = h * 320;
#pragma unroll 8
    for (int k = k0; k < k0 + 320; k++) s += mrow[k] * mergeW[(size_t)k * NH + f];
    if (h) red[f] = s;
    __syncthreads();
    if (!h) acc += s + red[f];
    __syncthreads();
  }
  if (!h) {
    float cnt = fmaxf((float)counts[g], 1.f);
    out[(size_t)g * NH + f] = acc / (3.f * cnt) + mergeb[f];
  }
}

// ---------------- host ----------------

struct Offs {
  size_t counts, gstart, deg, M, dinv, indptr, cursor, ent, wt, ydual, aff, tscan, th, tboff, perm;
  size_t yb[NCH], xo[NCH];
  size_t memset1_off, memset1_len, total;
};

static size_t build_offs(Offs& o, int Etot) {
  size_t off = 0;
  auto alloc = [&](size_t bytes) -> size_t {
    off = (off + 255) & ~(size_t)255;
    size_t s = off;
    off += bytes;
    return s;
  };
  o.counts = alloc(NG * 4);
  o.gstart = alloc(NG * 4);
  o.deg = alloc((size_t)4 * NN * 4);
  o.memset1_off = o.deg;
  o.memset1_len = (size_t)4 * NN * 4;  // only deg needs zeroing
  o.M = alloc((size_t)NLAY * NG * 640 * 4);  // fully overwritten by k_norm2
  o.dinv = alloc((size_t)4 * NN * 4);
  o.indptr = alloc((size_t)4 * (NN + 1) * 4);
  o.cursor = alloc((size_t)4 * (NN + 1) * 4);
  o.ent = alloc((size_t)Etot * 4);  // packed 4B entries
  o.wt = alloc((size_t)7 * NH * NH * 2);
  o.aff = alloc((size_t)NCH * NG * 2 * NH * 4);  // {mm, inv} per (chain, graph)
  o.tscan = alloc((size_t)160 * 4);   // tile sums [4][20] + tile offsets [4][20]
  o.th = alloc((size_t)20 * 256 * 4);    // per-tile degree histograms
  o.tboff = alloc((size_t)20 * 256 * 4); // per-(tile,bin) scatter offsets
  o.perm = alloc((size_t)NN * 4);        // degree-descending node permutation
  o.ydual = alloc((size_t)NN * 256 * 2);  // chains 0&4 interleaved
  for (int i = 1; i < 4; i++) o.yb[i] = alloc((size_t)NN * NH * 2);
  for (int i = 0; i < NCH; i++) {
    o.xo[i] = alloc((size_t)NNP * NH * 2);  // padded: fused gemm staging reads past NN
  }
  o.total = off;
  return off;
}

extern "C" void kernel_launch(void* const* d_in, const int* in_sizes, int n_in,
                              void* d_out, int out_size, void* d_ws, size_t ws_size,
                              hipStream_t stream) {
  if (n_in < 21) return;
  const float* x = (const float*)d_in[0];
  const float* embW = (const float*)d_in[1];
  const float* embb = (const float*)d_in[2];
  const float* mainW = (const float*)d_in[3];
  const float* mainb = (const float*)d_in[4];
  const float* maingw = (const float*)d_in[5];
  const float* maingb = (const float*)d_in[6];
  const float* maingms = (const float*)d_in[7];
  const float* locW = (const float*)d_in[8];
  const float* locb = (const float*)d_in[9];
  const float* locgw = (const float*)d_in[10];
  const float* locgb = (const float*)d_in[11];
  const float* locgms = (const float*)d_in[12];
  const float* mergeW = (const float*)d_in[13];
  const float* mergeb = (const float*)d_in[14];
  const int* edge_index = (const int*)d_in[15];
  // d_in[16] = edges0: permutation of edge_index under segment_sum -> reuse set 0
  const int* edges1 = (const int*)d_in[17];
  const int* edges2 = (const int*)d_in[18];
  const int* edges3 = (const int*)d_in[19];
  const int* batch = (const int*)d_in[20];

  int E0 = in_sizes[15] / 2;
  int E1 = in_sizes[17] / 2, E2 = in_sizes[18] / 2, E3 = in_sizes[19] / 2;
  int Etot = E0 + E1 + E2 + E3;
  int maxE = E0 > E1 ? E0 : E1;
  maxE = maxE > E2 ? maxE : E2;
  maxE = maxE > E3 ? maxE : E3;

  Offs o;
  if (build_offs(o, Etot) > ws_size) return;  // fail visibly

  char* ws = (char*)d_ws;
  int* counts = (int*)(ws + o.counts);
  int* gstart = (int*)(ws + o.gstart);
  int* deg = (int*)(ws + o.deg);
  float* M = (float*)(ws + o.M);
  float* dinv = (float*)(ws + o.dinv);
  int* indptr = (int*)(ws + o.indptr);
  int* cursor = (int*)(ws + o.cursor);
  u32* ent = (u32*)(ws + o.ent);
  u16* wt = (u16*)(ws + o.wt);
  float* aff = (float*)(ws + o.aff);
  int* tscan = (int*)(ws + o.tscan);
  int* th = (int*)(ws + o.th);
  int* tboff = (int*)(ws + o.tboff);
  int* perm = (int*)(ws + o.perm);
  u16* ydual = (u16*)(ws + o.ydual);
  u16 *yb[NCH], *xo[NCH];
  for (int i = 1; i < 4; i++) yb[i] = (u16*)(ws + o.yb[i]);
  for (int i = 0; i < NCH; i++) xo[i] = (u16*)(ws + o.xo[i]);

  ES4 es;
  es.e[0] = edge_index; es.e[1] = edges1; es.e[2] = edges2; es.e[3] = edges3;
  es.cnt[0] = E0; es.cnt[1] = E1; es.cnt[2] = E2; es.cnt[3] = E3;
  es.off[0] = 0; es.off[1] = E0; es.off[2] = E0 + E1; es.off[3] = E0 + E1 + E2;
  int4 entoff = make_int4(0, E0, E0 + E1, E0 + E1 + E2);

  hipMemsetAsync(ws + o.memset1_off, 0, o.memset1_len, stream);  // deg only
  k_setup<<<dim3((maxE + 255) / 256, 11), 256, 0, stream>>>(es, deg, embW, locW, mainW, wt);
  k_scanA<<<dim3(20, 4), 1024, 0, stream>>>(deg, indptr, dinv, tscan, th);
  k_scanB<<<1, 256, 0, stream>>>(tscan, tscan + 80, indptr, cursor, batch, counts, gstart,
                                 th, tboff);
  k_scanC<<<dim3(20, 4), 1024, 0, stream>>>(indptr, cursor, tscan + 80, deg, tboff, perm);
  k_fill<<<dim3((maxE + 255) / 256, 4), 256, 0, stream>>>(es, dinv, cursor, ent);

  const int nrb = (NN + 63) / 64;  // 313

  // fused embedding + layer-0 GEMMs -> ydual (both halves)
  k_gemm0<<<nrb, 256, 0, stream>>>(x, wt, embb, ydual);

  for (int l = 0; l < NLAY; l++) {
    int lp = (l > 0) ? (l - 1) : 0;  // previous layer's norm params (unused at l=0)
    ZP p = {};
    for (int zi = 0; zi < NCH; zi++) {
      bool isMain = (zi == 4);
      p.A[zi] = (const u16*)xo[zi];  // fused staging source: pre-norm of layer l-1
      p.W[zi] = wt + (size_t)((isMain ? 4 : 1) + l) * NH * NH;
      if (zi == 0) { p.Y[0] = ydual; p.ystride[0] = 256; }
      else if (zi == 4) { p.Y[4] = ydual + 128; p.ystride[4] = 256; }
      else { p.Y[zi] = yb[zi]; p.ystride[zi] = 128; }
      p.Xo[zi] = xo[zi];
      p.bias[zi] = (isMain ? mainb : locb) + (size_t)l * NH;
      p.gw[zi] = (isMain ? maingw : locgw) + (size_t)l * NH;
      p.gb[zi] = (isMain ? maingb : locgb) + (size_t)l * NH;
      p.gms[zi] = (isMain ? maingms : locgms) + (size_t)l * NH;
      p.pgw[zi] = (isMain ? maingw : locgw) + (size_t)lp * NH;
      p.pgb[zi] = (isMain ? maingb : locgb) + (size_t)lp * NH;
      p.colbase[zi] = isMain ? 512 : zi * NH;
    }
    if (l == 0) {
      // k_gemm0 already produced ydual; MST chains gather from chain-0 half
      p.Y[1] = ydual; p.Y[2] = ydual; p.Y[3] = ydual;
      p.ystride[1] = p.ystride[2] = p.ystride[3] = 256;
    } else {
      k_gemm_bf<<<dim3(nrb, NCH), 256, 0, stream>>>(p, batch, aff);
    }
    k_agg2<<<8750, 256, 0, stream>>>(p, indptr, ent, dinv, entoff, perm);
    k_norm2<<<dim3(NG, NCH, 4), 256, 0, stream>>>(p, gstart, counts,
                                                  M + (size_t)l * NG * 640,
                                                  (l == NLAY - 1) ? nullptr : aff);
  }

  k_mergeout<<<NG, 256, 0, stream>>>(M, mergeW, mergeb, counts, (float*)d_out);
}

// Round 10
// 367.239 us; speedup vs baseline: 1.3029x; 1.0330x over previous
//
#include <hip/hip_runtime.h>

#define NN 20000      // nodes
#define NNP 20032     // padded rows (64-row GEMM tiles read past NN)
#define NH 128        // hidden
#define NG 64         // graphs
#define NLAY 3
#define NCH 5         // 4 splits + main
#define GEPS 1e-5f
#define GSLOPE 0.01f

typedef unsigned short u16;
typedef unsigned int u32;
typedef __attribute__((ext_vector_type(8))) short short8;
typedef __attribute__((ext_vector_type(4))) float float4v;
typedef __attribute__((ext_vector_type(2))) float f32x2;

__device__ __forceinline__ u16 f2bf(float f) {
  union { float f; u32 u; } v; v.f = f;
  u32 r = (v.u + 0x7fffu + ((v.u >> 16) & 1u)) >> 16;
  return (u16)r;
}

struct ZP {
  const u16* A[NCH];     // GEMM input = Xo of previous layer (bf16, NN rows)
  const u16* W[NCH];     // GEMM weight, bf16 transposed [N][K]
  u16* Y[NCH];           // GEMM output / gather source (bf16)
  int ystride[NCH];      // row stride of Y in elements (256 for ydual, 128 else)
  u16* Xo[NCH];          // post-agg pre-norm (bf16, stride NH)
  const float* bias[NCH];
  const float* gw[NCH];  // this layer's norm weight (for k_norm2)
  const float* gb[NCH];
  const float* gms[NCH];
  const float* pgw[NCH]; // PREVIOUS layer's norm weight (for fused gemm staging)
  const float* pgb[NCH];
  int colbase[NCH];
};

struct ES4 {
  const int* e[4];
  int cnt[4];
  int off[4];
};

// ---------------- setup kernels ----------------

// r20: parallel two-phase scan (replaced 5-CU serial scan: −10.6 µs).
// r21/r22: LPT degree-desc perm REFUTED — even contention-free (r22), the
// scattered node mapping loses ent/indptr locality (+12 µs vs sequential).
// Sequential node = b*4+wv is the measured optimum; perm machinery removed.
__global__ __launch_bounds__(1024) void k_scanA(const int* __restrict__ deg,
                                                int* __restrict__ indptr,
                                                float* __restrict__ dinv,
                                                int* __restrict__ tsum) {
  int s = blockIdx.y, tile = blockIdx.x;
  int t = threadIdx.x;
  int idx = tile * 1024 + t;
  int v = 0;
  if (idx < NN) {
    v = deg[s * NN + idx];
    dinv[s * NN + idx] = rsqrtf((float)v + 1.0f);
  }
  int lane = t & 63, wv = t >> 6;  // 16 waves
  __shared__ int wsum[16];
  int x = v;
#pragma unroll
  for (int o = 1; o < 64; o <<= 1) {
    int y = __shfl_up(x, o);
    if (lane >= o) x += y;
  }
  if (lane == 63) wsum[wv] = x;
  __syncthreads();
  if (wv == 0) {
    int y = (lane < 16) ? wsum[lane] : 0;
#pragma unroll
    for (int o = 1; o < 16; o <<= 1) {
      int z = __shfl_up(y, o);
      if (lane >= o) y += z;
    }
    if (lane < 16) wsum[lane] = y;
  }
  __syncthreads();
  int waveoff = (wv == 0) ? 0 : wsum[wv - 1];
  int excl = waveoff + x - v;  // exclusive within tile
  if (idx < NN) indptr[s * (NN + 1) + idx] = excl;
  if (t == 1023) tsum[s * 20 + tile] = waveoff + x;  // tile total
}

__global__ __launch_bounds__(128) void k_scanB(const int* __restrict__ tsum,
                                               int* __restrict__ toff,
                                               int* __restrict__ indptr,
                                               int* __restrict__ cursor,
                                               const int* __restrict__ batch,
                                               int* __restrict__ counts,
                                               int* __restrict__ gstart) {
  int t = threadIdx.x;
  if (t < 4) {
    int run = 0;
    for (int i = 0; i < 20; i++) {
      toff[t * 20 + i] = run;
      run += tsum[t * 20 + i];
    }
    indptr[t * (NN + 1) + NN] = run;
    cursor[t * (NN + 1) + NN] = run;
  }
  if (t >= 64) {
    int g = t - 64;  // per-graph start/count via binary search (batch sorted)
    auto lb = [&](int key) {
      int lo = 0, hi = NN;
      while (lo < hi) {
        int mid = (lo + hi) >> 1;
        if (batch[mid] < key) lo = mid + 1; else hi = mid;
      }
      return lo;
    };
    int a = lb(g), b = lb(g + 1);
    gstart[g] = a;
    counts[g] = b - a;
  }
}

__global__ __launch_bounds__(1024) void k_scanC(int* __restrict__ indptr,
                                                int* __restrict__ cursor,
                                                const int* __restrict__ toff) {
  int s = blockIdx.y, tile = blockIdx.x;
  int idx = tile * 1024 + threadIdx.x;
  if (idx < NN) {
    int v = indptr[s * (NN + 1) + idx] + toff[s * 20 + tile];
    indptr[s * (NN + 1) + idx] = v;
    cursor[s * (NN + 1) + idx] = v;
  }
}

// packed entry: low 16 = src (NN < 2^16), high 16 = coef as bf16.
__global__ void k_fill(ES4 es, const float* __restrict__ dinv, int* __restrict__ cursor,
                       u32* __restrict__ ent) {
  int s = blockIdx.y;
  int i = blockIdx.x * 256 + threadIdx.x;
  int E = es.cnt[s];
  if (i >= E) return;
  int src = es.e[s][i];
  int dst = es.e[s][E + i];
  int pos = atomicAdd(&cursor[s * (NN + 1) + dst], 1);
  float c = dinv[s * NN + src] * dinv[s * NN + dst];
  ent[es.off[s] + pos] = (u32)src | ((u32)f2bf(c) << 16);
}

// fused setup: y<4 -> deg histogram for edge set y; y in 4..10 -> weight transpose
// fp32[K][N]->bf16[N][K] for mat y-4 (x<16).
__global__ __launch_bounds__(256) void k_setup(ES4 es, int* __restrict__ deg,
                                               const float* __restrict__ embW,
                                               const float* __restrict__ locW,
                                               const float* __restrict__ mainW,
                                               u16* __restrict__ wt) {
  int ybk = blockIdx.y;
  if (ybk < 4) {
    int s = ybk;
    int i = blockIdx.x * 256 + threadIdx.x;
    int E = es.cnt[s];
    if (i < E) atomicAdd(&deg[s * NN + es.e[s][E + i]], 1);
    return;
  }
  if (blockIdx.x >= 16) return;
  int mat = ybk - 4;
  const float* W = (mat == 0) ? embW : ((mat <= 3) ? locW + (mat - 1) * NH * NH
                                                   : mainW + (mat - 4) * NH * NH);
  int tile = blockIdx.x;
  int tk = (tile >> 2) * 32;
  int tn = (tile & 3) * 32;
  __shared__ float tl[32][33];
  int c = threadIdx.x & 31, r = threadIdx.x >> 5;
#pragma unroll
  for (int rr = 0; rr < 32; rr += 8)
    tl[r + rr][c] = W[(size_t)(tk + r + rr) * NH + tn + c];
  __syncthreads();
#pragma unroll
  for (int rr = 0; rr < 32; rr += 8)
    wt[(size_t)mat * NH * NH + (size_t)(tn + r + rr) * NH + tk + c] = f2bf(tl[c][r + rr]);
}

// ---------------- compute kernels ----------------

// Fused embedding + layer-0 GEMMs: per 64-row tile,
//   h = bf16(x) @ embW + embb       (h lives only in LDS, bf16)
//   ydual[:,0:128]   = h @ locW0    (shared by split chains 0..3)
//   ydual[:,128:256] = h @ mainW0
__global__ __launch_bounds__(256) void k_gemm0(const float* __restrict__ x,
                                               const u16* __restrict__ wt,
                                               const float* __restrict__ embb,
                                               u16* __restrict__ ydual) {
  __shared__ u16 As[64][136];
  __shared__ u16 Bs[128][136];
  int t = threadIdx.x;
  int row0 = blockIdx.x * 64;
  int c = t & 15, rs = t >> 4;
#pragma unroll
  for (int pass = 0; pass < 4; pass++) {
    int r = pass * 16 + rs;
    int gr = row0 + r;
    uint4 o = make_uint4(0, 0, 0, 0);
    if (gr < NN) {
      float4 a = *(const float4*)(x + (size_t)gr * NH + c * 8);
      float4 b = *(const float4*)(x + (size_t)gr * NH + c * 8 + 4);
      o.x = f2bf(a.x) | ((u32)f2bf(a.y) << 16);
      o.y = f2bf(a.z) | ((u32)f2bf(a.w) << 16);
      o.z = f2bf(b.x) | ((u32)f2bf(b.y) << 16);
      o.w = f2bf(b.z) | ((u32)f2bf(b.w) << 16);
    }
    *(uint4*)(&As[r][c * 8]) = o;
  }
#pragma unroll
  for (int pass = 0; pass < 8; pass++) {
    int n = pass * 16 + rs;
    *(uint4*)(&Bs[n][c * 8]) = *(const uint4*)(wt + (size_t)n * NH + c * 8);  // embW
  }
  __syncthreads();
  int lane = t & 63, w = t >> 6;
  int m16 = lane & 15, quad = lane >> 4;
  float4v acc[8];
#pragma unroll
  for (int i = 0; i < 8; i++) acc[i] = (float4v)(0.f);
#pragma unroll
  for (int kk = 0; kk < 4; kk++) {
    short8 av = *(const short8*)(&As[w * 16 + m16][kk * 32 + quad * 8]);
#pragma unroll
    for (int ct = 0; ct < 8; ct++) {
      short8 bv = *(const short8*)(&Bs[ct * 16 + m16][kk * 32 + quad * 8]);
      acc[ct] = __builtin_amdgcn_mfma_f32_16x16x32_bf16(av, bv, acc[ct], 0, 0, 0);
    }
  }
  __syncthreads();  // stage-1 LDS reads complete
#pragma unroll
  for (int ct = 0; ct < 8; ct++) {
    float bv = embb[ct * 16 + m16];
#pragma unroll
    for (int r = 0; r < 4; r++)
      As[w * 16 + quad * 4 + r][ct * 16 + m16] = f2bf(acc[ct][r] + bv);
  }
  {
    const u16* wl = wt + (size_t)1 * NH * NH;  // locW0
#pragma unroll
    for (int pass = 0; pass < 8; pass++) {
      int n = pass * 16 + rs;
      *(uint4*)(&Bs[n][c * 8]) = *(const uint4*)(wl + (size_t)n * NH + c * 8);
    }
  }
  __syncthreads();
  float4v acc0[8];
#pragma unroll
  for (int i = 0; i < 8; i++) acc0[i] = (float4v)(0.f);
#pragma unroll
  for (int kk = 0; kk < 4; kk++) {
    short8 av = *(const short8*)(&As[w * 16 + m16][kk * 32 + quad * 8]);
#pragma unroll
    for (int ct = 0; ct < 8; ct++) {
      short8 bv = *(const short8*)(&Bs[ct * 16 + m16][kk * 32 + quad * 8]);
      acc0[ct] = __builtin_amdgcn_mfma_f32_16x16x32_bf16(av, bv, acc0[ct], 0, 0, 0);
    }
  }
  __syncthreads();  // stage-2 Bs reads complete
  {
    const u16* wm = wt + (size_t)4 * NH * NH;  // mainW0
#pragma unroll
    for (int pass = 0; pass < 8; pass++) {
      int n = pass * 16 + rs;
      *(uint4*)(&Bs[n][c * 8]) = *(const uint4*)(wm + (size_t)n * NH + c * 8);
    }
  }
  __syncthreads();
  float4v acc4[8];
#pragma unroll
  for (int i = 0; i < 8; i++) acc4[i] = (float4v)(0.f);
#pragma unroll
  for (int kk = 0; kk < 4; kk++) {
    short8 av = *(const short8*)(&As[w * 16 + m16][kk * 32 + quad * 8]);
#pragma unroll
    for (int ct = 0; ct < 8; ct++) {
      short8 bv = *(const short8*)(&Bs[ct * 16 + m16][kk * 32 + quad * 8]);
      acc4[ct] = __builtin_amdgcn_mfma_f32_16x16x32_bf16(av, bv, acc4[ct], 0, 0, 0);
    }
  }
  __syncthreads();  // stage-3 LDS reads complete; As/Bs free for bounce
#pragma unroll
  for (int ct = 0; ct < 8; ct++) {
#pragma unroll
    for (int r = 0; r < 4; r++) {
      As[w * 16 + quad * 4 + r][ct * 16 + m16] = f2bf(acc0[ct][r]);
      Bs[w * 16 + quad * 4 + r][ct * 16 + m16] = f2bf(acc4[ct][r]);
    }
  }
  __syncthreads();
#pragma unroll
  for (int pass = 0; pass < 4; pass++) {
    int r = pass * 16 + rs;
    int gr = row0 + r;
    if (gr < NN) {
      *(uint4*)(ydual + (size_t)gr * 256 + c * 8) = *(const uint4*)(&As[r][c * 8]);
      *(uint4*)(ydual + (size_t)gr * 256 + 128 + c * 8) = *(const uint4*)(&Bs[r][c * 8]);
    }
  }
}

// Y[z] = norm_affine(Xo_prev[z]) @ Wt[z]^T. The previous layer's graph-norm +
// leaky is applied during A-staging from per-(chain,graph) {mm=ms*mean, inv}
// (aff buffer) + layer params (pgw/pgb). Expression shape matches k_norm2's old
// Xn path exactly -> bf16-rounded A operand is bit-identical (r15 fusion:
// removes the 102 MB Xn write+read round trip).
__global__ __launch_bounds__(256) void k_gemm_bf(ZP p, const int* __restrict__ batch,
                                                 const float* __restrict__ aff) {
  int zi = blockIdx.y;
  const u16* __restrict__ X = p.A[zi];
  const u16* __restrict__ Wt = p.W[zi];
  u16* __restrict__ Y = p.Y[zi];
  const float* __restrict__ gw = p.pgw[zi];
  const float* __restrict__ gb = p.pgb[zi];
  int yst = p.ystride[zi];
  __shared__ u16 As[64][136];   // +8 pad: 2-way bank aliasing only
  __shared__ u16 Bs[128][136];
  int t = threadIdx.x;
  int row0 = blockIdx.x * 64;
  int c = t & 15, rs = t >> 4;
  float4 wA = *(const float4*)(gw + c * 8);
  float4 wB = *(const float4*)(gw + c * 8 + 4);
  float4 bA = *(const float4*)(gb + c * 8);
  float4 bB = *(const float4*)(gb + c * 8 + 4);
  float wv8[8] = {wA.x, wA.y, wA.z, wA.w, wB.x, wB.y, wB.z, wB.w};
  float bv8[8] = {bA.x, bA.y, bA.z, bA.w, bB.x, bB.y, bB.z, bB.w};
#pragma unroll
  for (int pass = 0; pass < 4; pass++) {
    int r = pass * 16 + rs;
    int gr = row0 + r;
    int grc = (gr < NN) ? gr : (NN - 1);  // clamp: stores are guarded anyway
    int gg = batch[grc];
    const float* ab = aff + ((size_t)zi * NG + gg) * 2 * NH;
    uint4 xv = *(const uint4*)(X + (size_t)grc * NH + c * 8);
    float4 mA = *(const float4*)(ab + c * 8);
    float4 mB = *(const float4*)(ab + c * 8 + 4);
    float4 iA = *(const float4*)(ab + NH + c * 8);
    float4 iB = *(const float4*)(ab + NH + c * 8 + 4);
    float mm[8] = {mA.x, mA.y, mA.z, mA.w, mB.x, mB.y, mB.z, mB.w};
    float iv[8] = {iA.x, iA.y, iA.z, iA.w, iB.x, iB.y, iB.z, iB.w};
    u32 xw[4] = {xv.x, xv.y, xv.z, xv.w};
    uint4 ou;
    u32* op = (u32*)&ou;
#pragma unroll
    for (int j = 0; j < 4; j++) {
      float v0 = __uint_as_float(xw[j] << 16);
      float v1 = __uint_as_float(xw[j] & 0xffff0000u);
      float o0 = wv8[2 * j] * (v0 - mm[2 * j]) * iv[2 * j] + bv8[2 * j];
      float o1 = wv8[2 * j + 1] * (v1 - mm[2 * j + 1]) * iv[2 * j + 1] + bv8[2 * j + 1];
      o0 = (o0 >= 0.f) ? o0 : GSLOPE * o0;
      o1 = (o1 >= 0.f) ? o1 : GSLOPE * o1;
      op[j] = (u32)f2bf(o0) | ((u32)f2bf(o1) << 16);
    }
    *(uint4*)(&As[r][c * 8]) = ou;
  }
#pragma unroll
  for (int pass = 0; pass < 8; pass++) {
    int n = pass * 16 + rs;
    *(uint4*)(&Bs[n][c * 8]) = *(const uint4*)(Wt + (size_t)n * NH + c * 8);
  }
  __syncthreads();
  int lane = t & 63, w = t >> 6;
  int m16 = lane & 15, quad = lane >> 4;
  float4v acc[8];
#pragma unroll
  for (int i = 0; i < 8; i++) acc[i] = (float4v)(0.f);
#pragma unroll
  for (int kk = 0; kk < 4; kk++) {
    short8 av = *(const short8*)(&As[w * 16 + m16][kk * 32 + quad * 8]);
#pragma unroll
    for (int ct = 0; ct < 8; ct++) {
      short8 bv = *(const short8*)(&Bs[ct * 16 + m16][kk * 32 + quad * 8]);
      acc[ct] = __builtin_amdgcn_mfma_f32_16x16x32_bf16(av, bv, acc[ct], 0, 0, 0);
    }
  }
  __syncthreads();
  // epilogue: C/D layout col=lane&15, row=quad*4+reg -> LDS bounce -> 16B stores
#pragma unroll
  for (int ct = 0; ct < 8; ct++) {
#pragma unroll
    for (int r = 0; r < 4; r++) {
      As[w * 16 + quad * 4 + r][ct * 16 + m16] = f2bf(acc[ct][r]);
    }
  }
  __syncthreads();
#pragma unroll
  for (int pass = 0; pass < 4; pass++) {
    int r = pass * 16 + rs;
    int gr = row0 + r;
    if (gr < NN) *(uint4*)(Y + (size_t)gr * yst + c * 8) = *(const uint4*)(&As[r][c * 8]);
  }
}

__device__ __forceinline__ f32x2 bf2x2(u32 v) {
  f32x2 r;
  r.x = __uint_as_float(v << 16);
  r.y = __uint_as_float(v & 0xffff0000u);
  return r;
}

// packed float2 FMA payload (targets v_pk_fma_f32)
__device__ __forceinline__ void fma8p(f32x2* a, uint4 v, float cf) {
  f32x2 c2; c2.x = cf; c2.y = cf;
  a[0] += c2 * bf2x2(v.x);
  a[1] += c2 * bf2x2(v.y);
  a[2] += c2 * bf2x2(v.z);
  a[3] += c2 * bf2x2(v.w);
}

// self term + bias, pack -> Xo (no stats here: per-element global atomics are
// ~100x more expensive than per-block-reduced work on MI355X — round 7 lesson,
// re-confirmed r21 with the contended perm scatter)
__device__ __forceinline__ void fin_chain(const float* a, const u16* Yb, int st, int node,
                                          int fo, float d2, const float* bias,
                                          u16* __restrict__ Xo) {
  uint4 sv = *(const uint4*)(Yb + (size_t)node * st + fo);
  float s[8] = {
    __uint_as_float(sv.x << 16), __uint_as_float(sv.x & 0xffff0000u),
    __uint_as_float(sv.y << 16), __uint_as_float(sv.y & 0xffff0000u),
    __uint_as_float(sv.z << 16), __uint_as_float(sv.z & 0xffff0000u),
    __uint_as_float(sv.w << 16), __uint_as_float(sv.w & 0xffff0000u)};
  float4 b0 = *(const float4*)(bias + fo);
  float4 b1 = *(const float4*)(bias + fo + 4);
  float bb[8] = {b0.x, b0.y, b0.z, b0.w, b1.x, b1.y, b1.z, b1.w};
  float o[8];
#pragma unroll
  for (int j = 0; j < 8; j++) o[j] = a[j] + d2 * s[j] + bb[j];
  uint4 ou;
  u32* op = (u32*)&ou;
#pragma unroll
  for (int j = 0; j < 4; j++)
    op[j] = (u32)f2bf(o[2 * j]) | ((u32)f2bf(o[2 * j + 1]) << 16);
  *(uint4*)(Xo + (size_t)node * NH + fo) = ou;
}

// GCN aggregate, compacted 1-D grid (8750 blocks) — round-12 measured optimum,
// r23 final form. Refuted levers (record): r14 4x unroll (VGPR cliff), r16
// sub-line feature chunking (2x line traffic), r13 chain steering (null),
// r17 nt-hint (null), r19 ent prefetch (null), r21/r22 LPT degree-sorted
// mapping (−12 µs: scattered nodes lose ent/indptr locality — sequential
// node = b*4+wv is optimal). At a latency x occupancy x VALU equilibrium.
//   blocks 0..4999: chains 0&4 FUSED on interleaved ydual (shared entry loads +
//     addr math), 4 nodes/block (wave each), 4 edge-groups x 16 lanes,
//     2x unroll + shuffle reduce, ent prefetch pipeline.
//   blocks 5000..8749: MST chain 1..3 (avg deg~2), 16 nodes/block:
//     one 16-lane group per node, 2x-unrolled pair loop, no shuffles.
__global__ __launch_bounds__(256) void k_agg2(ZP p, const int* __restrict__ indptr,
                                              const u32* __restrict__ ent,
                                              const float* __restrict__ dinv, int4 entoff) {
  int b = blockIdx.x;
  int wv = threadIdx.x >> 6, lane = threadIdx.x & 63;
  int g = lane >> 4;
  int fo = (lane & 15) * 8;
  if (b < 5000) {
    int node = b * 4 + wv;
    // dual: chains 0 and 4 interleaved in ydual (stride 256; Y4 = Y0 + 128)
    int beg = indptr[node], end = indptr[node + 1];
    const u16* __restrict__ Y0 = p.Y[0];
    const u16* __restrict__ Y4 = p.Y[4];
    int st = p.ystride[0];
    f32x2 a0[4], a4[4];
#pragma unroll
    for (int j = 0; j < 4; j++) { a0[j] = (f32x2)(0.f); a4[j] = (f32x2)(0.f); }
    int e = beg + g;
    if (e + 4 < end) {
      u32 sa = __builtin_nontemporal_load(ent + e);
      u32 sb = __builtin_nontemporal_load(ent + e + 4);
      while (e + 4 < end) {
        u32 na = __builtin_nontemporal_load(ent + e + 8);
        u32 nb = __builtin_nontemporal_load(ent + e + 12);
        size_t ra = (size_t)(sa & 0xffffu) * st + fo;
        size_t rb = (size_t)(sb & 0xffffu) * st + fo;
        uint4 va0 = *(const uint4*)(Y0 + ra);
        uint4 va4 = *(const uint4*)(Y4 + ra);
        uint4 vb0 = *(const uint4*)(Y0 + rb);
        uint4 vb4 = *(const uint4*)(Y4 + rb);
        float ca = __uint_as_float(sa & 0xffff0000u);
        float cb = __uint_as_float(sb & 0xffff0000u);
        fma8p(a0, va0, ca); fma8p(a4, va4, ca);
        fma8p(a0, vb0, cb); fma8p(a4, vb4, cb);
        e += 8;
        sa = na; sb = nb;
      }
    }
    if (e < end) {
      u32 sc = __builtin_nontemporal_load(ent + e);
      float cf = __uint_as_float(sc & 0xffff0000u);
      size_t ro = (size_t)(sc & 0xffffu) * st + fo;
      uint4 v0 = *(const uint4*)(Y0 + ro);
      uint4 v4 = *(const uint4*)(Y4 + ro);
      fma8p(a0, v0, cf);
      fma8p(a4, v4, cf);
    }
    float* f0 = (float*)a0;
    float* f4 = (float*)a4;
#pragma unroll
    for (int j = 0; j < 8; j++) {
      f0[j] += __shfl_xor(f0[j], 16);
      f0[j] += __shfl_xor(f0[j], 32);
      f4[j] += __shfl_xor(f4[j], 16);
      f4[j] += __shfl_xor(f4[j], 32);
    }
    if (g == 0) {
      float di = dinv[node];
      float d2 = di * di;
      fin_chain(f0, Y0, st, node, fo, d2, p.bias[0], p.Xo[0]);
      fin_chain(f4, Y4, st, node, fo, d2, p.bias[4], p.Xo[4]);
    }
  } else {
    int mb = b - 5000;
    int s = 1 + mb / 1250;       // chain == edge set, 1..3
    int node = (mb % 1250) * 16 + wv * 4 + g;  // 1250*16 == NN exactly
    const int* ip = indptr + s * (NN + 1);
    int eb = (s == 1) ? entoff.y : ((s == 2) ? entoff.z : entoff.w);
    const u16* __restrict__ Y = p.Y[s];
    int st = p.ystride[s];
    int beg = ip[node], end = ip[node + 1];
    const u32* __restrict__ ev = ent + eb;
    f32x2 a[4];
#pragma unroll
    for (int j = 0; j < 4; j++) a[j] = (f32x2)(0.f);
    int e = beg;
    for (; e + 1 < end; e += 2) {
      u32 s0 = ev[e];      // same addr across the 16-lane group -> one fetch
      u32 s1 = ev[e + 1];
      uint4 v0 = *(const uint4*)(Y + (size_t)(s0 & 0xffffu) * st + fo);
      uint4 v1 = *(const uint4*)(Y + (size_t)(s1 & 0xffffu) * st + fo);
      fma8p(a, v0, __uint_as_float(s0 & 0xffff0000u));
      fma8p(a, v1, __uint_as_float(s1 & 0xffff0000u));
    }
    if (e < end) {
      u32 sc = ev[e];
      uint4 v = *(const uint4*)(Y + (size_t)(sc & 0xffffu) * st + fo);
      fma8p(a, v, __uint_as_float(sc & 0xffff0000u));
    }
    float di = dinv[s * NN + node];
    float d2 = di * di;
    fin_chain((float*)a, Y, st, node, fo, d2, p.bias[s], p.Xo[s]);
  }
}

// fused graph-norm: grid (NG, NCH, 4 feature-chunks), 256 thr = 16 feature-pairs
// x 16 row-streams — measured optimum (r18's 64-feature+LDS-cache variant cost
// 21 µs: fewer blocks + 47 KB LDS dropped occupancy while pass-2 reads were
// L2-hot anyway; parallelism > re-read elimination here). Two passes over the
// graph's contiguous row slab (batch is sorted): stats via LDS tree (zero
// atomics), then leaky+M-sum. No Xn store (r15) — affine {mm, inv} goes to aff
// for the next layer's fused GEMM staging.
__global__ __launch_bounds__(256) void k_norm2(ZP p, const int* __restrict__ gstart,
                                               const int* __restrict__ counts,
                                               float* __restrict__ Ml,
                                               float* __restrict__ aff) {
  int g = blockIdx.x, zi = blockIdx.y, fc = blockIdx.z;
  const u16* __restrict__ X = p.Xo[zi];
  int t = threadIdx.x;
  int fj = t & 15;
  int f2 = fc * 32 + fj * 2;
  int rh = t >> 4;  // 16 row streams
  int start = gstart[g], cnt = counts[g];
  __shared__ float red[4][16][17];
  float s0 = 0.f, s1 = 0.f, q0 = 0.f, q1 = 0.f;
  for (int i = rh; i < cnt; i += 16) {
    u32 v = *(const u32*)(X + (size_t)(start + i) * NH + f2);
    float v0 = __uint_as_float(v << 16), v1 = __uint_as_float(v & 0xffff0000u);
    s0 += v0; q0 += v0 * v0;
    s1 += v1; q1 += v1 * v1;
  }
  red[0][rh][fj] = s0; red[1][rh][fj] = s1;
  red[2][rh][fj] = q0; red[3][rh][fj] = q1;
  __syncthreads();
#pragma unroll
  for (int off = 8; off >= 1; off >>= 1) {
    if (rh < off) {
      red[0][rh][fj] += red[0][rh + off][fj];
      red[1][rh][fj] += red[1][rh + off][fj];
      red[2][rh][fj] += red[2][rh + off][fj];
      red[3][rh][fj] += red[3][rh + off][fj];
    }
    __syncthreads();
  }
  float cntf = fmaxf((float)cnt, 1.f);
  float w0 = p.gw[zi][f2], w1 = p.gw[zi][f2 + 1];
  float b0 = p.gb[zi][f2], b1 = p.gb[zi][f2 + 1];
  float ms0 = p.gms[zi][f2], ms1 = p.gms[zi][f2 + 1];
  float mean0 = red[0][0][fj] / cntf, mean1 = red[1][0][fj] / cntf;
  float mm0 = ms0 * mean0, mm1 = ms1 * mean1;
  float var0 = red[2][0][fj] / cntf - (2.f * ms0 - ms0 * ms0) * mean0 * mean0;
  float var1 = red[3][0][fj] / cntf - (2.f * ms1 - ms1 * ms1) * mean1 * mean1;
  float inv0 = rsqrtf(var0 + GEPS), inv1 = rsqrtf(var1 + GEPS);
  __syncthreads();  // all reads of red done before reuse
  float m0 = 0.f, m1 = 0.f;
  for (int i = rh; i < cnt; i += 16) {
    size_t ro = (size_t)(start + i) * NH + f2;
    u32 v = *(const u32*)(X + ro);
    float v0 = __uint_as_float(v << 16), v1 = __uint_as_float(v & 0xffff0000u);
    float o0 = w0 * (v0 - mm0) * inv0 + b0;
    float o1 = w1 * (v1 - mm1) * inv1 + b1;
    o0 = (o0 >= 0.f) ? o0 : GSLOPE * o0;
    o1 = (o1 >= 0.f) ? o1 : GSLOPE * o1;
    m0 += o0; m1 += o1;
  }
  red[0][rh][fj] = m0; red[1][rh][fj] = m1;
  __syncthreads();
#pragma unroll
  for (int off = 8; off >= 1; off >>= 1) {
    if (rh < off) {
      red[0][rh][fj] += red[0][rh + off][fj];
      red[1][rh][fj] += red[1][rh + off][fj];
    }
    __syncthreads();
  }
  if (rh == 0) {
    int col = p.colbase[zi] + f2;
    Ml[(size_t)g * 640 + col] = red[0][0][fj];
    Ml[(size_t)g * 640 + col + 1] = red[1][0][fj];
    if (aff) {
      float* ab = aff + ((size_t)zi * NG + g) * 2 * NH;
      ab[f2] = mm0; ab[f2 + 1] = mm1;
      ab[NH + f2] = inv0; ab[NH + f2 + 1] = inv1;
    }
  }
}

// out[g][f] = mean_l(M[l][g][:] @ mergeW[:,f]) / cnt + mergeb[f]
__global__ __launch_bounds__(256) void k_mergeout(const float* __restrict__ M,
                                                  const float* __restrict__ mergeW,
                                                  const float* __restrict__ mergeb,
                                                  const int* __restrict__ counts,
                                                  float* __restrict__ out) {
  int g = blockIdx.x;
  int f = threadIdx.x & 127, h = threadIdx.x >> 7;
  __shared__ float mrow[640];
  __shared__ float red[128];
  float acc = 0.f;
  for (int l = 0; l < NLAY; l++) {
    const float* Mr = M + ((size_t)l * NG + g) * 640;
    for (int i = threadIdx.x; i < 640; i += 256) mrow[i] = Mr[i];
    __syncthreads();
    float s = 0.f;
    int k0 = h * 320;
#pragma unroll 8
    for (int k = k0; k < k0 + 320; k++) s += mrow[k] * mergeW[(size_t)k * NH + f];
    if (h) red[f] = s;
    __syncthreads();
    if (!h) acc += s + red[f];
    __syncthreads();
  }
  if (!h) {
    float cnt = fmaxf((float)counts[g], 1.f);
    out[(size_t)g * NH + f] = acc / (3.f * cnt) + mergeb[f];
  }
}

// ---------------- host ----------------

struct Offs {
  size_t counts, gstart, deg, M, dinv, indptr, cursor, ent, wt, ydual, aff, tscan;
  size_t yb[NCH], xo[NCH];
  size_t memset1_off, memset1_len, total;
};

static size_t build_offs(Offs& o, int Etot) {
  size_t off = 0;
  auto alloc = [&](size_t bytes) -> size_t {
    off = (off + 255) & ~(size_t)255;
    size_t s = off;
    off += bytes;
    return s;
  };
  o.counts = alloc(NG * 4);
  o.gstart = alloc(NG * 4);
  o.deg = alloc((size_t)4 * NN * 4);
  o.memset1_off = o.deg;
  o.memset1_len = (size_t)4 * NN * 4;  // only deg needs zeroing
  o.M = alloc((size_t)NLAY * NG * 640 * 4);  // fully overwritten by k_norm2
  o.dinv = alloc((size_t)4 * NN * 4);
  o.indptr = alloc((size_t)4 * (NN + 1) * 4);
  o.cursor = alloc((size_t)4 * (NN + 1) * 4);
  o.ent = alloc((size_t)Etot * 4);  // packed 4B entries
  o.wt = alloc((size_t)7 * NH * NH * 2);
  o.aff = alloc((size_t)NCH * NG * 2 * NH * 4);  // {mm, inv} per (chain, graph)
  o.tscan = alloc((size_t)160 * 4);  // tile sums [4][20] + tile offsets [4][20]
  o.ydual = alloc((size_t)NN * 256 * 2);  // chains 0&4 interleaved
  for (int i = 1; i < 4; i++) o.yb[i] = alloc((size_t)NN * NH * 2);
  for (int i = 0; i < NCH; i++) {
    o.xo[i] = alloc((size_t)NNP * NH * 2);  // padded: fused gemm staging reads past NN
  }
  o.total = off;
  return off;
}

extern "C" void kernel_launch(void* const* d_in, const int* in_sizes, int n_in,
                              void* d_out, int out_size, void* d_ws, size_t ws_size,
                              hipStream_t stream) {
  if (n_in < 21) return;
  const float* x = (const float*)d_in[0];
  const float* embW = (const float*)d_in[1];
  const float* embb = (const float*)d_in[2];
  const float* mainW = (const float*)d_in[3];
  const float* mainb = (const float*)d_in[4];
  const float* maingw = (const float*)d_in[5];
  const float* maingb = (const float*)d_in[6];
  const float* maingms = (const float*)d_in[7];
  const float* locW = (const float*)d_in[8];
  const float* locb = (const float*)d_in[9];
  const float* locgw = (const float*)d_in[10];
  const float* locgb = (const float*)d_in[11];
  const float* locgms = (const float*)d_in[12];
  const float* mergeW = (const float*)d_in[13];
  const float* mergeb = (const float*)d_in[14];
  const int* edge_index = (const int*)d_in[15];
  // d_in[16] = edges0: permutation of edge_index under segment_sum -> reuse set 0
  const int* edges1 = (const int*)d_in[17];
  const int* edges2 = (const int*)d_in[18];
  const int* edges3 = (const int*)d_in[19];
  const int* batch = (const int*)d_in[20];

  int E0 = in_sizes[15] / 2;
  int E1 = in_sizes[17] / 2, E2 = in_sizes[18] / 2, E3 = in_sizes[19] / 2;
  int Etot = E0 + E1 + E2 + E3;
  int maxE = E0 > E1 ? E0 : E1;
  maxE = maxE > E2 ? maxE : E2;
  maxE = maxE > E3 ? maxE : E3;

  Offs o;
  if (build_offs(o, Etot) > ws_size) return;  // fail visibly

  char* ws = (char*)d_ws;
  int* counts = (int*)(ws + o.counts);
  int* gstart = (int*)(ws + o.gstart);
  int* deg = (int*)(ws + o.deg);
  float* M = (float*)(ws + o.M);
  float* dinv = (float*)(ws + o.dinv);
  int* indptr = (int*)(ws + o.indptr);
  int* cursor = (int*)(ws + o.cursor);
  u32* ent = (u32*)(ws + o.ent);
  u16* wt = (u16*)(ws + o.wt);
  float* aff = (float*)(ws + o.aff);
  int* tscan = (int*)(ws + o.tscan);
  u16* ydual = (u16*)(ws + o.ydual);
  u16 *yb[NCH], *xo[NCH];
  for (int i = 1; i < 4; i++) yb[i] = (u16*)(ws + o.yb[i]);
  for (int i = 0; i < NCH; i++) xo[i] = (u16*)(ws + o.xo[i]);

  ES4 es;
  es.e[0] = edge_index; es.e[1] = edges1; es.e[2] = edges2; es.e[3] = edges3;
  es.cnt[0] = E0; es.cnt[1] = E1; es.cnt[2] = E2; es.cnt[3] = E3;
  es.off[0] = 0; es.off[1] = E0; es.off[2] = E0 + E1; es.off[3] = E0 + E1 + E2;
  int4 entoff = make_int4(0, E0, E0 + E1, E0 + E1 + E2);

  hipMemsetAsync(ws + o.memset1_off, 0, o.memset1_len, stream);  // deg only
  k_setup<<<dim3((maxE + 255) / 256, 11), 256, 0, stream>>>(es, deg, embW, locW, mainW, wt);
  k_scanA<<<dim3(20, 4), 1024, 0, stream>>>(deg, indptr, dinv, tscan);
  k_scanB<<<1, 128, 0, stream>>>(tscan, tscan + 80, indptr, cursor, batch, counts, gstart);
  k_scanC<<<dim3(20, 4), 1024, 0, stream>>>(indptr, cursor, tscan + 80);
  k_fill<<<dim3((maxE + 255) / 256, 4), 256, 0, stream>>>(es, dinv, cursor, ent);

  const int nrb = (NN + 63) / 64;  // 313

  // fused embedding + layer-0 GEMMs -> ydual (both halves)
  k_gemm0<<<nrb, 256, 0, stream>>>(x, wt, embb, ydual);

  for (int l = 0; l < NLAY; l++) {
    int lp = (l > 0) ? (l - 1) : 0;  // previous layer's norm params (unused at l=0)
    ZP p = {};
    for (int zi = 0; zi < NCH; zi++) {
      bool isMain = (zi == 4);
      p.A[zi] = (const u16*)xo[zi];  // fused staging source: pre-norm of layer l-1
      p.W[zi] = wt + (size_t)((isMain ? 4 : 1) + l) * NH * NH;
      if (zi == 0) { p.Y[0] = ydual; p.ystride[0] = 256; }
      else if (zi == 4) { p.Y[4] = ydual + 128; p.ystride[4] = 256; }
      else { p.Y[zi] = yb[zi]; p.ystride[zi] = 128; }
      p.Xo[zi] = xo[zi];
      p.bias[zi] = (isMain ? mainb : locb) + (size_t)l * NH;
      p.gw[zi] = (isMain ? maingw : locgw) + (size_t)l * NH;
      p.gb[zi] = (isMain ? maingb : locgb) + (size_t)l * NH;
      p.gms[zi] = (isMain ? maingms : locgms) + (size_t)l * NH;
      p.pgw[zi] = (isMain ? maingw : locgw) + (size_t)lp * NH;
      p.pgb[zi] = (isMain ? maingb : locgb) + (size_t)lp * NH;
      p.colbase[zi] = isMain ? 512 : zi * NH;
    }
    if (l == 0) {
      // k_gemm0 already produced ydual; MST chains gather from chain-0 half
      p.Y[1] = ydual; p.Y[2] = ydual; p.Y[3] = ydual;
      p.ystride[1] = p.ystride[2] = p.ystride[3] = 256;
    } else {
      k_gemm_bf<<<dim3(nrb, NCH), 256, 0, stream>>>(p, batch, aff);
    }
    k_agg2<<<8750, 256, 0, stream>>>(p, indptr, ent, dinv, entoff);
    k_norm2<<<dim3(NG, NCH, 4), 256, 0, stream>>>(p, gstart, counts,
                                                  M + (size_t)l * NG * 640,
                                                  (l == NLAY - 1) ? nullptr : aff);
  }

  k_mergeout<<<NG, 256, 0, stream>>>(M, mergeW, mergeb, counts, (float*)d_out);
}